// Round 7
// baseline (255.650 us; speedup 1.0000x reference)
//
#include <hip/hip_runtime.h>

// ChildSum TreeLSTM, complete 4-ary tree. N=65536, D=300(->320), H=256, K=4.
// Leaves = [16384,65536). Children of [s,e) are contiguous [4s+1,4e+1).
// Round 7: unified 128x128-tile MFMA GEMM core (64x64 wave tiles, acc[4][4]);
// conv_x eliminated (f32->bf16 conversion fused into A-staging);
// leaf gates fused in epilogue via interleaved I/U B-rows + shfl_xor pairing.

#define NTOT 65536
#define DD   300
#define KP   320
#define HH   256
#define LEAF_START 16384

typedef unsigned short u16;
typedef unsigned int   u32;
typedef __attribute__((ext_vector_type(8))) short bf16x8;
typedef __attribute__((ext_vector_type(4))) float f32x4;

union BF8 { bf16x8 v; u16 u[8]; };

// ---- ws layout (bytes) ----
#define OFF_HB    0ull                                   // [65537][256] bf16
#define OFF_C     33554944ull                            // [65537][256] f32
#define OFF_PRE   100664832ull                           // [16384][768] bf16
#define OFF_WXB   125830656ull                           // [768][320] bf16
#define OFF_WHB   126322176ull                           // [768][256] bf16
#define OFF_UNION 126715392ull
#define OFF_PIU   (OFF_UNION)                            // [11008][512] bf16
#define OFF_PF    (OFF_UNION + 11272192ull)              // [43776][256] bf16
#define OFF_HSUM  (OFF_UNION + 33685504ull)              // [11008][256] bf16

__device__ __forceinline__ float sigm(float x) { return 1.f / (1.f + __expf(-x)); }
__device__ __forceinline__ float ftanh(float x) {
    x = fminf(15.f, fmaxf(-15.f, x));
    float e = __expf(2.f * x);
    return (e - 1.f) / (e + 1.f);
}
__device__ __forceinline__ u16 f2bf(float f) {
    union { float f; u32 u; } v; v.f = f;
    u32 r = v.u + 0x7fffu + ((v.u >> 16) & 1u);
    return (u16)(r >> 16);
}
__device__ __forceinline__ float bf2f(u16 b) {
    union { u32 u; float f; } v; v.u = ((u32)b) << 16;
    return v.f;
}
__device__ __forceinline__ int lidx(int r, int g) { return (r << 3) | (g ^ (r & 7)); }

// ---- zero the pad row (node index 65536) ----
__global__ __launch_bounds__(256) void zero_pad(u16* __restrict__ hb,
                                                float* __restrict__ c) {
    const int t = threadIdx.x;
    hb[(size_t)NTOT * HH + t] = 0;
    c [(size_t)NTOT * HH + t] = 0.f;
}

// ---- stack [ixw; uxw; fiw] -> Wxb [768][320] bf16 ----
__global__ __launch_bounds__(256) void conv_wx(const float* __restrict__ ixw,
                                               const float* __restrict__ uxw,
                                               const float* __restrict__ fiw,
                                               u32* __restrict__ W2) {
    const int total = 768 * (KP / 2);
    for (int id = blockIdx.x * 256 + threadIdx.x; id < total;
         id += gridDim.x * 256) {
        const int row = id / (KP / 2);
        const int k   = (id % (KP / 2)) * 2;
        const float* src = (row < 256) ? (ixw + (size_t)row * DD)
                         : (row < 512) ? (uxw + (size_t)(row - 256) * DD)
                                       : (fiw + (size_t)(row - 512) * DD);
        const float f0 = (k < DD)     ? src[k]     : 0.f;
        const float f1 = (k + 1 < DD) ? src[k + 1] : 0.f;
        W2[id] = (u32)f2bf(f0) | ((u32)f2bf(f1) << 16);
    }
}

// ---- stack [ihw; uhw; fhw] -> Whb [768][256] bf16 ----
__global__ __launch_bounds__(256) void conv_wh(const float* __restrict__ ihw,
                                               const float* __restrict__ uhw,
                                               const float* __restrict__ fhw,
                                               u32* __restrict__ W2) {
    const int total = 768 * (HH / 2);
    for (int id = blockIdx.x * 256 + threadIdx.x; id < total;
         id += gridDim.x * 256) {
        const int row = id / (HH / 2);
        const int k   = (id % (HH / 2)) * 2;
        const float* src = (row < 256) ? (ihw + (size_t)row * HH)
                         : (row < 512) ? (uhw + (size_t)(row - 256) * HH)
                                       : (fhw + (size_t)(row - 512) * HH);
        W2[id] = (u32)f2bf(src[k]) | ((u32)f2bf(src[k + 1]) << 16);
    }
}

// ---- stage one A-granule from f32 X with bf16 conversion ----
__device__ __forceinline__ bf16x8 load_x_granule(const float* __restrict__ src,
                                                 int k) {
    BF8 pk;
    if (k + 8 <= DD) {
        const float4 f0 = *(const float4*)(src + k);
        const float4 f1 = *(const float4*)(src + k + 4);
        pk.u[0] = f2bf(f0.x); pk.u[1] = f2bf(f0.y);
        pk.u[2] = f2bf(f0.z); pk.u[3] = f2bf(f0.w);
        pk.u[4] = f2bf(f1.x); pk.u[5] = f2bf(f1.y);
        pk.u[6] = f2bf(f1.z); pk.u[7] = f2bf(f1.w);
    } else if (k < DD) {             // straddle: k = 296 (296..299 valid)
        const float4 f0 = *(const float4*)(src + k);
        pk.u[0] = f2bf(f0.x); pk.u[1] = f2bf(f0.y);
        pk.u[2] = f2bf(f0.z); pk.u[3] = f2bf(f0.w);
        pk.u[4] = 0; pk.u[5] = 0; pk.u[6] = 0; pk.u[7] = 0;
    } else {
        #pragma unroll
        for (int j = 0; j < 8; ++j) pk.u[j] = 0;
    }
    return pk.v;
}

// ---- leaf GEMM: [49152 x 320(f32 X)] x [320 x 128 interleaved I/U], fused gates ----
__global__ __launch_bounds__(256) void leaf_gemm(
    const float* __restrict__ X, const u16* __restrict__ Wxb,
    const float* __restrict__ ixb, const float* __restrict__ ihb,
    const float* __restrict__ uxb, const float* __restrict__ uhb,
    u16* __restrict__ hb, float* __restrict__ c)
{
    __shared__ bf16x8 Ash[1024];
    __shared__ bf16x8 Bsh[1024];

    const int tid  = threadIdx.x;
    const int lane = tid & 63;
    const int w    = tid >> 6;
    const int wr   = w >> 1, wc = w & 1;
    const int m16  = lane & 15, q = lane >> 4;

    const int row0   = LEAF_START + blockIdx.x * 128;
    const int chbase = blockIdx.y * 64;

    const bf16x8* __restrict__ Wv = (const bf16x8*)Wxb;   // 40 granules/row

    f32x4 acc[4][4];
    #pragma unroll
    for (int mf = 0; mf < 4; ++mf)
        #pragma unroll
        for (int nf = 0; nf < 4; ++nf) acc[mf][nf] = (f32x4)0.f;

    for (int kt = 0; kt < 5; ++kt) {
        __syncthreads();
        #pragma unroll
        for (int i = 0; i < 4; ++i) {               // A: 1024 granules
            const int G = tid + i * 256;
            const int r = G >> 3, g = G & 7;
            const int k = kt * 64 + g * 8;
            Ash[lidx(r, g)] = load_x_granule(X + (size_t)(row0 + r) * DD, k);
        }
        #pragma unroll
        for (int i = 0; i < 4; ++i) {               // B: interleaved I/U rows
            const int G = tid + i * 256;
            const int br = G >> 3, g = G & 7;
            const int ch = chbase + (br >> 1);
            const int srow = ch + ((br & 1) << 8);  // even->ix row, odd->ux row
            Bsh[lidx(br, g)] = Wv[(size_t)srow * 40 + kt * 8 + g];
        }
        __syncthreads();

        #pragma unroll
        for (int ks = 0; ks < 2; ++ks) {
            const int kg = ks * 4 + q;
            bf16x8 a[4], b[4];
            #pragma unroll
            for (int mf = 0; mf < 4; ++mf)
                a[mf] = Ash[lidx(wr * 64 + mf * 16 + m16, kg)];
            #pragma unroll
            for (int nf = 0; nf < 4; ++nf)
                b[nf] = Bsh[lidx(wc * 64 + nf * 16 + m16, kg)];
            #pragma unroll
            for (int mf = 0; mf < 4; ++mf)
                #pragma unroll
                for (int nf = 0; nf < 4; ++nf)
                    acc[mf][nf] = __builtin_amdgcn_mfma_f32_16x16x32_bf16(
                        a[mf], b[nf], acc[mf][nf], 0, 0, 0);
        }
    }

    // epilogue: adjacent lanes hold I/U of the same channel
    const bool evn = (m16 & 1) == 0;
    #pragma unroll
    for (int nf = 0; nf < 4; ++nf) {
        const int ch = chbase + wc * 32 + nf * 8 + (m16 >> 1);
        const float bi = ixb[ch] + ihb[ch];   // recurrent biases apply at leaves
        const float bu = uxb[ch] + uhb[ch];
        #pragma unroll
        for (int mf = 0; mf < 4; ++mf) {
            #pragma unroll
            for (int r4 = 0; r4 < 4; ++r4) {
                const float mine = acc[mf][nf][r4];
                const float oth  = __shfl_xor(mine, 1, 64);
                const float aI = evn ? mine : oth;
                const float aU = evn ? oth : mine;
                const float cn = sigm(aI + bi) * ftanh(aU + bu);
                const int node = row0 + wr * 64 + mf * 16 + q * 4 + r4;
                const size_t off = (size_t)node * HH + ch;
                if (evn) c[off] = cn;
                else     hb[off] = f2bf(ftanh(cn));
            }
        }
    }
}

// ---- input-proj GEMM: [16384 x 320(f32 X)] x [320 x 768] -> pre bf16 ----
__global__ __launch_bounds__(256) void proj_gemm(const float* __restrict__ X,
                                                 const u16* __restrict__ Wxb,
                                                 u16* __restrict__ pre)
{
    __shared__ bf16x8 Ash[1024];
    __shared__ bf16x8 Bsh[1024];

    const int tid  = threadIdx.x;
    const int lane = tid & 63;
    const int w    = tid >> 6;
    const int wr   = w >> 1, wc = w & 1;
    const int m16  = lane & 15, q = lane >> 4;

    const int row0 = blockIdx.x * 128;
    const int n0   = blockIdx.y * 128;

    const bf16x8* __restrict__ Wv = (const bf16x8*)Wxb;

    f32x4 acc[4][4];
    #pragma unroll
    for (int mf = 0; mf < 4; ++mf)
        #pragma unroll
        for (int nf = 0; nf < 4; ++nf) acc[mf][nf] = (f32x4)0.f;

    for (int kt = 0; kt < 5; ++kt) {
        __syncthreads();
        #pragma unroll
        for (int i = 0; i < 4; ++i) {
            const int G = tid + i * 256;
            const int r = G >> 3, g = G & 7;
            const int k = kt * 64 + g * 8;
            Ash[lidx(r, g)] = load_x_granule(X + (size_t)(row0 + r) * DD, k);
        }
        #pragma unroll
        for (int i = 0; i < 4; ++i) {
            const int G = tid + i * 256;
            const int br = G >> 3, g = G & 7;
            Bsh[lidx(br, g)] = Wv[(size_t)(n0 + br) * 40 + kt * 8 + g];
        }
        __syncthreads();

        #pragma unroll
        for (int ks = 0; ks < 2; ++ks) {
            const int kg = ks * 4 + q;
            bf16x8 a[4], b[4];
            #pragma unroll
            for (int mf = 0; mf < 4; ++mf)
                a[mf] = Ash[lidx(wr * 64 + mf * 16 + m16, kg)];
            #pragma unroll
            for (int nf = 0; nf < 4; ++nf)
                b[nf] = Bsh[lidx(wc * 64 + nf * 16 + m16, kg)];
            #pragma unroll
            for (int mf = 0; mf < 4; ++mf)
                #pragma unroll
                for (int nf = 0; nf < 4; ++nf)
                    acc[mf][nf] = __builtin_amdgcn_mfma_f32_16x16x32_bf16(
                        a[mf], b[nf], acc[mf][nf], 0, 0, 0);
        }
    }

    #pragma unroll
    for (int mf = 0; mf < 4; ++mf) {
        #pragma unroll
        for (int nf = 0; nf < 4; ++nf) {
            const int col = n0 + wc * 64 + nf * 16 + m16;
            #pragma unroll
            for (int r4 = 0; r4 < 4; ++r4) {
                const int node = row0 + wr * 64 + mf * 16 + q * 4 + r4;
                pre[(size_t)node * 768 + col] = f2bf(acc[mf][nf][r4]);
            }
        }
    }
}

// ---- per-level: hsum (bf16) ----
__global__ __launch_bounds__(256) void hsum_kernel(const u16* __restrict__ hb,
                                                   u16* __restrict__ hsumb,
                                                   int crow0, int L)
{
    const int id = blockIdx.x * 256 + threadIdx.x;
    if (id >= L * 64) return;
    const int nloc = id >> 6;
    const int cu   = (id & 63) << 1;
    const u32* __restrict__ src = (const u32*)hb;
    float s0 = 0.f, s1 = 0.f, s2 = 0.f, s3 = 0.f;
    #pragma unroll
    for (int k = 0; k < 4; ++k) {
        const size_t ro = (size_t)(crow0 + 4 * nloc + k) * (HH / 2) + cu;
        const u32 a = src[ro], b = src[ro + 1];
        s0 += bf2f((u16)(a & 0xffff)); s1 += bf2f((u16)(a >> 16));
        s2 += bf2f((u16)(b & 0xffff)); s3 += bf2f((u16)(b >> 16));
    }
    u32* __restrict__ dst = (u32*)hsumb;
    const size_t oo = (size_t)nloc * (HH / 2) + cu;
    dst[oo]     = (u32)f2bf(s0) | ((u32)f2bf(s1) << 16);
    dst[oo + 1] = (u32)f2bf(s2) | ((u32)f2bf(s3) << 16);
}

// ---- per-level recurrent GEMM (IU + F segments), 128x128 tiles ----
__global__ __launch_bounds__(256) void rec_gemm(const u16* __restrict__ hb,
                                                const u16* __restrict__ hsumb,
                                                const u16* __restrict__ Whb,
                                                u16* __restrict__ projIU,
                                                u16* __restrict__ projF,
                                                int crow0, int L)
{
    __shared__ bf16x8 Ash[1024];
    __shared__ bf16x8 Bsh[1024];

    const int nIUrb = (L + 127) >> 7;
    const int bid   = blockIdx.x;

    bool isIU; int rb, cb;
    if (bid < nIUrb * 4) { isIU = true;  rb = bid >> 2; cb = bid & 3; }
    else { isIU = false; const int b2 = bid - nIUrb * 4; rb = b2 >> 1; cb = b2 & 1; }

    const int row0  = rb * 128;
    const int Brow0 = isIU ? cb * 128 : 512 + cb * 128;
    const int ocol0 = cb * 128;
    u16* __restrict__ out = isIU ? projIU : projF;
    const int ostride = isIU ? 512 : 256;

    const int tid  = threadIdx.x;
    const int lane = tid & 63;
    const int w    = tid >> 6;
    const int wr   = w >> 1, wc = w & 1;
    const int m16  = lane & 15, q = lane >> 4;

    const bf16x8* __restrict__ Av = isIU ? (const bf16x8*)hsumb : (const bf16x8*)hb;
    const bf16x8* __restrict__ Wv = (const bf16x8*)Whb;   // 32 granules/row

    f32x4 acc[4][4];
    #pragma unroll
    for (int mf = 0; mf < 4; ++mf)
        #pragma unroll
        for (int nf = 0; nf < 4; ++nf) acc[mf][nf] = (f32x4)0.f;

    for (int kt = 0; kt < 4; ++kt) {
        __syncthreads();
        #pragma unroll
        for (int i = 0; i < 4; ++i) {
            const int G = tid + i * 256;
            const int r = G >> 3, g = G & 7;
            int srow = row0 + r;
            if (!isIU) { srow = crow0 + srow; if (srow > NTOT) srow = NTOT; }
            Ash[lidx(r, g)] = Av[(size_t)srow * 32 + kt * 8 + g];
        }
        #pragma unroll
        for (int i = 0; i < 4; ++i) {
            const int G = tid + i * 256;
            const int br = G >> 3, g = G & 7;
            Bsh[lidx(br, g)] = Wv[(size_t)(Brow0 + br) * 32 + kt * 8 + g];
        }
        __syncthreads();

        #pragma unroll
        for (int ks = 0; ks < 2; ++ks) {
            const int kg = ks * 4 + q;
            bf16x8 a[4], b[4];
            #pragma unroll
            for (int mf = 0; mf < 4; ++mf)
                a[mf] = Ash[lidx(wr * 64 + mf * 16 + m16, kg)];
            #pragma unroll
            for (int nf = 0; nf < 4; ++nf)
                b[nf] = Bsh[lidx(wc * 64 + nf * 16 + m16, kg)];
            #pragma unroll
            for (int mf = 0; mf < 4; ++mf)
                #pragma unroll
                for (int nf = 0; nf < 4; ++nf)
                    acc[mf][nf] = __builtin_amdgcn_mfma_f32_16x16x32_bf16(
                        a[mf], b[nf], acc[mf][nf], 0, 0, 0);
        }
    }

    #pragma unroll
    for (int mf = 0; mf < 4; ++mf) {
        #pragma unroll
        for (int nf = 0; nf < 4; ++nf) {
            const int col = ocol0 + wc * 64 + nf * 16 + m16;
            #pragma unroll
            for (int r4 = 0; r4 < 4; ++r4) {
                const int orow = row0 + wr * 64 + mf * 16 + q * 4 + r4;
                out[(size_t)orow * ostride + col] = f2bf(acc[mf][nf][r4]);
            }
        }
    }
}

// ---- per-level gates (f32 math) ----
__global__ __launch_bounds__(256) void gate_kernel(
    const u16* __restrict__ pre, const u16* __restrict__ projIU,
    const u16* __restrict__ projF,
    const float* __restrict__ ixb, const float* __restrict__ ihb,
    const float* __restrict__ uxb, const float* __restrict__ uhb,
    const float* __restrict__ fib, const float* __restrict__ fhb,
    u16* __restrict__ hb, float* __restrict__ c, float* __restrict__ out,
    int s, int crow0)
{
    const int nloc = blockIdx.x;
    const int j    = threadIdx.x;
    const int n    = s + nloc;

    const float aI = bf2f(pre[(size_t)n * 768 + j]) + ixb[j] + ihb[j]
                   + bf2f(projIU[(size_t)nloc * 512 + j]);
    const float aU = bf2f(pre[(size_t)n * 768 + 256 + j]) + uxb[j] + uhb[j]
                   + bf2f(projIU[(size_t)nloc * 512 + 256 + j]);
    const float fpre = bf2f(pre[(size_t)n * 768 + 512 + j]) + fib[j] + fhb[j];

    float fc = 0.f;
    #pragma unroll
    for (int k = 0; k < 4; ++k) {
        const float fg = sigm(fpre + bf2f(projF[(size_t)(4 * nloc + k) * 256 + j]));
        fc = fmaf(fg, c[(size_t)(crow0 + 4 * nloc + k) * HH + j], fc);
    }
    const float cn = fmaf(sigm(aI), ftanh(aU), fc);
    const float hn = ftanh(cn);
    hb[(size_t)n * HH + j] = f2bf(hn);
    c [(size_t)n * HH + j] = cn;
    if (n == 0) { out[j] = hn; out[HH + j] = cn; }
}

extern "C" void kernel_launch(void* const* d_in, const int* in_sizes, int n_in,
                              void* d_out, int out_size, void* d_ws, size_t ws_size,
                              hipStream_t stream) {
    const float* X   = (const float*)d_in[0];
    const float* ixw = (const float*)d_in[1];
    const float* ixb = (const float*)d_in[2];
    const float* ihw = (const float*)d_in[3];
    const float* ihb = (const float*)d_in[4];
    const float* uxw = (const float*)d_in[5];
    const float* uxb = (const float*)d_in[6];
    const float* uhw = (const float*)d_in[7];
    const float* uhb = (const float*)d_in[8];
    const float* fiw = (const float*)d_in[9];
    const float* fib = (const float*)d_in[10];
    const float* fhw = (const float*)d_in[11];
    const float* fhb = (const float*)d_in[12];
    float* out = (float*)d_out;

    char* ws = (char*)d_ws;
    u16*   hb    = (u16*)(ws + OFF_HB);
    float* cbuf  = (float*)(ws + OFF_C);
    u16*   pre   = (u16*)(ws + OFF_PRE);
    u16*   Wxb   = (u16*)(ws + OFF_WXB);
    u16*   Whb   = (u16*)(ws + OFF_WHB);
    u16*   pIU   = (u16*)(ws + OFF_PIU);
    u16*   pF    = (u16*)(ws + OFF_PF);
    u16*   hsumb = (u16*)(ws + OFF_HSUM);

    zero_pad<<<1, 256, 0, stream>>>(hb, cbuf);
    conv_wx<<<480, 256, 0, stream>>>(ixw, uxw, fiw, (u32*)Wxb);
    conv_wh<<<384, 256, 0, stream>>>(ihw, uhw, fhw, (u32*)Whb);

    leaf_gemm<<<dim3(384, 4), 256, 0, stream>>>(X, Wxb, ixb, ihb, uxb, uhb, hb, cbuf);
    proj_gemm<<<dim3(128, 6), 256, 0, stream>>>(X, Wxb, pre);

    const int starts[8] = {5461, 1365, 341, 85, 21, 5, 1, 0};
    const int ends[8]   = {16384, 5461, 1365, 341, 85, 21, 5, 1};
    for (int l = 0; l < 8; ++l) {
        const int s = starts[l], e = ends[l];
        const int L = e - s;
        const int crow0 = 4 * s + 1;
        const int nIUrb = (L + 127) >> 7;
        const int nFrb  = (4 * L + 127) >> 7;
        hsum_kernel<<<(L * 64 + 255) / 256, 256, 0, stream>>>(hb, hsumb, crow0, L);
        rec_gemm<<<nIUrb * 4 + nFrb * 2, 256, 0, stream>>>(hb, hsumb, Whb, pIU, pF, crow0, L);
        gate_kernel<<<L, 256, 0, stream>>>(pre, pIU, pF,
            ixb, ihb, uxb, uhb, fib, fhb, hb, cbuf, out, s, crow0);
    }
}

// Round 8
// 232.969 us; speedup vs baseline: 1.0974x; 1.0974x over previous
//
#include <hip/hip_runtime.h>

// ChildSum TreeLSTM, complete 4-ary tree. N=65536, D=300(->320), H=256, K=4.
// Leaves = [16384,65536). Children of [s,e) are contiguous [4s+1,4e+1).
// Round 8: 128x128 MFMA tiles everywhere, bf16 Xb precomputed (conv_x),
// leaf B-tile = [64ix|64ux] same channels (full-lane epilogue), hsum fused
// into rec_gemm A-staging. 21 launches total.

#define NTOT 65536
#define DD   300
#define KP   320
#define HH   256
#define LEAF_START 16384

typedef unsigned short u16;
typedef unsigned int   u32;
typedef __attribute__((ext_vector_type(8))) short bf16x8;
typedef __attribute__((ext_vector_type(4))) float f32x4;

union BF8 { bf16x8 v; u16 u[8]; };

// ---- ws layout (bytes) ----
#define OFF_HB    0ull                                   // [65537][256] bf16
#define OFF_C     33554944ull                            // [65537][256] f32
#define OFF_PRE   100664832ull                           // [16384][768] bf16
#define OFF_WXB   125830656ull                           // [768][320] bf16
#define OFF_WHB   126322176ull                           // [768][256] bf16
#define OFF_UNION 126715392ull
#define OFF_XB    (OFF_UNION)                            // [65536][320] bf16
#define OFF_PIU   (OFF_UNION + 41943040ull)              // [11008][512] bf16
#define OFF_PF    (OFF_UNION + 53215232ull)              // [43776][256] bf16

__device__ __forceinline__ float sigm(float x) { return 1.f / (1.f + __expf(-x)); }
__device__ __forceinline__ float ftanh(float x) {
    x = fminf(15.f, fmaxf(-15.f, x));
    float e = __expf(2.f * x);
    return (e - 1.f) / (e + 1.f);
}
__device__ __forceinline__ u16 f2bf(float f) {
    union { float f; u32 u; } v; v.f = f;
    u32 r = v.u + 0x7fffu + ((v.u >> 16) & 1u);
    return (u16)(r >> 16);
}
__device__ __forceinline__ float bf2f(u16 b) {
    union { u32 u; float f; } v; v.u = ((u32)b) << 16;
    return v.f;
}
__device__ __forceinline__ int lidx(int r, int g) { return (r << 3) | (g ^ (r & 7)); }

// ---- X [N][300] f32 -> Xb [N][320] bf16 ----
__global__ __launch_bounds__(256) void conv_x(const float* __restrict__ X,
                                              u32* __restrict__ Xb2) {
    const size_t total = (size_t)NTOT * (KP / 2);
    for (size_t id = (size_t)blockIdx.x * 256 + threadIdx.x; id < total;
         id += (size_t)gridDim.x * 256) {
        const int node = (int)(id / (KP / 2));
        const int k    = ((int)(id % (KP / 2))) * 2;
        const float f0 = (k < DD)     ? X[(size_t)node * DD + k]     : 0.f;
        const float f1 = (k + 1 < DD) ? X[(size_t)node * DD + k + 1] : 0.f;
        Xb2[id] = (u32)f2bf(f0) | ((u32)f2bf(f1) << 16);
    }
}

// ---- stack [ixw; uxw; fiw] -> Wxb [768][320] bf16 ----
__global__ __launch_bounds__(256) void conv_wx(const float* __restrict__ ixw,
                                               const float* __restrict__ uxw,
                                               const float* __restrict__ fiw,
                                               u32* __restrict__ W2) {
    const int total = 768 * (KP / 2);
    for (int id = blockIdx.x * 256 + threadIdx.x; id < total;
         id += gridDim.x * 256) {
        const int row = id / (KP / 2);
        const int k   = (id % (KP / 2)) * 2;
        const float* src = (row < 256) ? (ixw + (size_t)row * DD)
                         : (row < 512) ? (uxw + (size_t)(row - 256) * DD)
                                       : (fiw + (size_t)(row - 512) * DD);
        const float f0 = (k < DD)     ? src[k]     : 0.f;
        const float f1 = (k + 1 < DD) ? src[k + 1] : 0.f;
        W2[id] = (u32)f2bf(f0) | ((u32)f2bf(f1) << 16);
    }
}

// ---- stack [ihw; uhw; fhw] -> Whb [768][256] bf16; block 0 zeroes pad row ----
__global__ __launch_bounds__(256) void conv_wh(const float* __restrict__ ihw,
                                               const float* __restrict__ uhw,
                                               const float* __restrict__ fhw,
                                               u32* __restrict__ W2,
                                               u16* __restrict__ hb,
                                               float* __restrict__ c) {
    if (blockIdx.x == 0) {
        const int t = threadIdx.x;
        hb[(size_t)NTOT * HH + t] = 0;
        c [(size_t)NTOT * HH + t] = 0.f;
    }
    const int total = 768 * (HH / 2);
    for (int id = blockIdx.x * 256 + threadIdx.x; id < total;
         id += gridDim.x * 256) {
        const int row = id / (HH / 2);
        const int k   = (id % (HH / 2)) * 2;
        const float* src = (row < 256) ? (ihw + (size_t)row * HH)
                         : (row < 512) ? (uhw + (size_t)(row - 256) * HH)
                                       : (fhw + (size_t)(row - 512) * HH);
        W2[id] = (u32)f2bf(src[k]) | ((u32)f2bf(src[k + 1]) << 16);
    }
}

// ---- leaf GEMM: 128 nodes x 64 channels; B = [64 ix | 64 ux] same channels ----
// Fused gates: c = sigm(aI+bi)*tanh(aU+bu); h = tanh(c).
__global__ __launch_bounds__(256) void leaf_gemm(
    const u16* __restrict__ Xb, const u16* __restrict__ Wxb,
    const float* __restrict__ ixb, const float* __restrict__ ihb,
    const float* __restrict__ uxb, const float* __restrict__ uhb,
    u16* __restrict__ hb, float* __restrict__ c)
{
    __shared__ bf16x8 Ash[1024];   // 128 rows x 8 k-granules
    __shared__ bf16x8 Bsh[1024];   // 128 B-rows x 8

    const int tid  = threadIdx.x;
    const int lane = tid & 63;
    const int w    = tid >> 6;
    const int wr   = w >> 1, wc = w & 1;     // 2 node-halves x 2 channel-halves
    const int m16  = lane & 15, q = lane >> 4;

    const int row0   = LEAF_START + blockIdx.x * 128;
    const int chbase = blockIdx.y * 64;

    const bf16x8* __restrict__ Xv = (const bf16x8*)Xb;   // 40 granules/row
    const bf16x8* __restrict__ Wv = (const bf16x8*)Wxb;

    f32x4 accI[4][2], accU[4][2];
    #pragma unroll
    for (int mf = 0; mf < 4; ++mf)
        #pragma unroll
        for (int nf = 0; nf < 2; ++nf) { accI[mf][nf] = (f32x4)0.f; accU[mf][nf] = (f32x4)0.f; }

    for (int kt = 0; kt < 5; ++kt) {
        __syncthreads();
        #pragma unroll
        for (int i = 0; i < 4; ++i) {               // A
            const int G = tid + i * 256;
            const int r = G >> 3, g = G & 7;
            Ash[lidx(r, g)] = Xv[(size_t)(row0 + r) * 40 + kt * 8 + g];
        }
        #pragma unroll
        for (int i = 0; i < 4; ++i) {               // B: 0..63 ix, 64..127 ux
            const int G = tid + i * 256;
            const int br = G >> 3, g = G & 7;
            const int srow = ((br >> 6) << 8) + chbase + (br & 63);
            Bsh[lidx(br, g)] = Wv[(size_t)srow * 40 + kt * 8 + g];
        }
        __syncthreads();

        #pragma unroll
        for (int ks = 0; ks < 2; ++ks) {
            const int kg = ks * 4 + q;
            bf16x8 a[4], bI[2], bU[2];
            #pragma unroll
            for (int mf = 0; mf < 4; ++mf)
                a[mf] = Ash[lidx(wr * 64 + mf * 16 + m16, kg)];
            #pragma unroll
            for (int nf = 0; nf < 2; ++nf) {
                bI[nf] = Bsh[lidx(wc * 32 + nf * 16 + m16, kg)];
                bU[nf] = Bsh[lidx(64 + wc * 32 + nf * 16 + m16, kg)];
            }
            #pragma unroll
            for (int mf = 0; mf < 4; ++mf)
                #pragma unroll
                for (int nf = 0; nf < 2; ++nf) {
                    accI[mf][nf] = __builtin_amdgcn_mfma_f32_16x16x32_bf16(
                        a[mf], bI[nf], accI[mf][nf], 0, 0, 0);
                    accU[mf][nf] = __builtin_amdgcn_mfma_f32_16x16x32_bf16(
                        a[mf], bU[nf], accU[mf][nf], 0, 0, 0);
                }
        }
    }

    // epilogue: ch = chbase + wc*32 + nf*16 + m16; node = row0 + wr*64 + mf*16 + q*4 + r4
    #pragma unroll
    for (int nf = 0; nf < 2; ++nf) {
        const int ch = chbase + wc * 32 + nf * 16 + m16;
        const float bi = ixb[ch] + ihb[ch];   // recurrent biases apply at leaves
        const float bu = uxb[ch] + uhb[ch];
        #pragma unroll
        for (int mf = 0; mf < 4; ++mf) {
            #pragma unroll
            for (int r4 = 0; r4 < 4; ++r4) {
                const float cn = sigm(accI[mf][nf][r4] + bi) * ftanh(accU[mf][nf][r4] + bu);
                const int node = row0 + wr * 64 + mf * 16 + q * 4 + r4;
                const size_t off = (size_t)node * HH + ch;
                c [off] = cn;
                hb[off] = f2bf(ftanh(cn));
            }
        }
    }
}

// ---- input-proj GEMM: [16384 x 320] x [320 x 768] -> pre bf16 ----
__global__ __launch_bounds__(256) void proj_gemm(const u16* __restrict__ Xb,
                                                 const u16* __restrict__ Wxb,
                                                 u16* __restrict__ pre)
{
    __shared__ bf16x8 Ash[1024];
    __shared__ bf16x8 Bsh[1024];

    const int tid  = threadIdx.x;
    const int lane = tid & 63;
    const int w    = tid >> 6;
    const int wr   = w >> 1, wc = w & 1;
    const int m16  = lane & 15, q = lane >> 4;

    const int row0 = blockIdx.x * 128;
    const int n0   = blockIdx.y * 128;

    const bf16x8* __restrict__ Xv = (const bf16x8*)Xb;
    const bf16x8* __restrict__ Wv = (const bf16x8*)Wxb;

    f32x4 acc[4][4];
    #pragma unroll
    for (int mf = 0; mf < 4; ++mf)
        #pragma unroll
        for (int nf = 0; nf < 4; ++nf) acc[mf][nf] = (f32x4)0.f;

    for (int kt = 0; kt < 5; ++kt) {
        __syncthreads();
        #pragma unroll
        for (int i = 0; i < 4; ++i) {
            const int G = tid + i * 256;
            const int r = G >> 3, g = G & 7;
            Ash[lidx(r, g)] = Xv[(size_t)(row0 + r) * 40 + kt * 8 + g];
        }
        #pragma unroll
        for (int i = 0; i < 4; ++i) {
            const int G = tid + i * 256;
            const int br = G >> 3, g = G & 7;
            Bsh[lidx(br, g)] = Wv[(size_t)(n0 + br) * 40 + kt * 8 + g];
        }
        __syncthreads();

        #pragma unroll
        for (int ks = 0; ks < 2; ++ks) {
            const int kg = ks * 4 + q;
            bf16x8 a[4], b[4];
            #pragma unroll
            for (int mf = 0; mf < 4; ++mf)
                a[mf] = Ash[lidx(wr * 64 + mf * 16 + m16, kg)];
            #pragma unroll
            for (int nf = 0; nf < 4; ++nf)
                b[nf] = Bsh[lidx(wc * 64 + nf * 16 + m16, kg)];
            #pragma unroll
            for (int mf = 0; mf < 4; ++mf)
                #pragma unroll
                for (int nf = 0; nf < 4; ++nf)
                    acc[mf][nf] = __builtin_amdgcn_mfma_f32_16x16x32_bf16(
                        a[mf], b[nf], acc[mf][nf], 0, 0, 0);
        }
    }

    #pragma unroll
    for (int mf = 0; mf < 4; ++mf)
        #pragma unroll
        for (int nf = 0; nf < 4; ++nf) {
            const int col = n0 + wc * 64 + nf * 16 + m16;
            #pragma unroll
            for (int r4 = 0; r4 < 4; ++r4) {
                const int node = row0 + wr * 64 + mf * 16 + q * 4 + r4;
                pre[(size_t)node * 768 + col] = f2bf(acc[mf][nf][r4]);
            }
        }
}

// ---- per-level recurrent GEMM; hsum computed in A-staging (IU path) ----
__global__ __launch_bounds__(256) void rec_gemm(const u16* __restrict__ hb,
                                                const u16* __restrict__ Whb,
                                                u16* __restrict__ projIU,
                                                u16* __restrict__ projF,
                                                int crow0, int L)
{
    __shared__ bf16x8 Ash[1024];
    __shared__ bf16x8 Bsh[1024];

    const int nIUrb = (L + 127) >> 7;
    const int bid   = blockIdx.x;

    bool isIU; int rb, cb;
    if (bid < nIUrb * 4) { isIU = true;  rb = bid >> 2; cb = bid & 3; }
    else { isIU = false; const int b2 = bid - nIUrb * 4; rb = b2 >> 1; cb = b2 & 1; }

    const int row0  = rb * 128;
    const int Brow0 = isIU ? cb * 128 : 512 + cb * 128;
    const int ocol0 = cb * 128;
    u16* __restrict__ out = isIU ? projIU : projF;
    const int ostride = isIU ? 512 : 256;

    const int tid  = threadIdx.x;
    const int lane = tid & 63;
    const int w    = tid >> 6;
    const int wr   = w >> 1, wc = w & 1;
    const int m16  = lane & 15, q = lane >> 4;

    const bf16x8* __restrict__ Hv = (const bf16x8*)hb;   // 32 granules/row
    const bf16x8* __restrict__ Wv = (const bf16x8*)Whb;

    f32x4 acc[4][4];
    #pragma unroll
    for (int mf = 0; mf < 4; ++mf)
        #pragma unroll
        for (int nf = 0; nf < 4; ++nf) acc[mf][nf] = (f32x4)0.f;

    for (int kt = 0; kt < 4; ++kt) {
        __syncthreads();
        #pragma unroll
        for (int i = 0; i < 4; ++i) {
            const int G = tid + i * 256;
            const int r = G >> 3, g = G & 7;
            bf16x8 val;
            if (isIU) {
                if (row0 + r < L) {
                    // hsum of 4 contiguous children, f32 accumulate, RNE pack
                    const size_t cg0 = (size_t)(crow0 + 4 * (row0 + r)) * 32 + kt * 8 + g;
                    BF8 x0, x1, x2, x3, o;
                    x0.v = Hv[cg0]; x1.v = Hv[cg0 + 32];
                    x2.v = Hv[cg0 + 64]; x3.v = Hv[cg0 + 96];
                    #pragma unroll
                    for (int j = 0; j < 8; ++j)
                        o.u[j] = f2bf(bf2f(x0.u[j]) + bf2f(x1.u[j])
                                    + bf2f(x2.u[j]) + bf2f(x3.u[j]));
                    val = o.v;
                } else {
                    BF8 z;
                    #pragma unroll
                    for (int j = 0; j < 8; ++j) z.u[j] = 0;
                    val = z.v;
                }
            } else {
                int srow = crow0 + row0 + r;
                if (srow > NTOT) srow = NTOT;    // zeroed pad row
                val = Hv[(size_t)srow * 32 + kt * 8 + g];
            }
            Ash[lidx(r, g)] = val;
        }
        #pragma unroll
        for (int i = 0; i < 4; ++i) {
            const int G = tid + i * 256;
            const int br = G >> 3, g = G & 7;
            Bsh[lidx(br, g)] = Wv[(size_t)(Brow0 + br) * 32 + kt * 8 + g];
        }
        __syncthreads();

        #pragma unroll
        for (int ks = 0; ks < 2; ++ks) {
            const int kg = ks * 4 + q;
            bf16x8 a[4], b[4];
            #pragma unroll
            for (int mf = 0; mf < 4; ++mf)
                a[mf] = Ash[lidx(wr * 64 + mf * 16 + m16, kg)];
            #pragma unroll
            for (int nf = 0; nf < 4; ++nf)
                b[nf] = Bsh[lidx(wc * 64 + nf * 16 + m16, kg)];
            #pragma unroll
            for (int mf = 0; mf < 4; ++mf)
                #pragma unroll
                for (int nf = 0; nf < 4; ++nf)
                    acc[mf][nf] = __builtin_amdgcn_mfma_f32_16x16x32_bf16(
                        a[mf], b[nf], acc[mf][nf], 0, 0, 0);
        }
    }

    #pragma unroll
    for (int mf = 0; mf < 4; ++mf)
        #pragma unroll
        for (int nf = 0; nf < 4; ++nf) {
            const int col = ocol0 + wc * 64 + nf * 16 + m16;
            #pragma unroll
            for (int r4 = 0; r4 < 4; ++r4) {
                const int orow = row0 + wr * 64 + mf * 16 + q * 4 + r4;
                out[(size_t)orow * ostride + col] = f2bf(acc[mf][nf][r4]);
            }
        }
}

// ---- per-level gates (f32 math) ----
__global__ __launch_bounds__(256) void gate_kernel(
    const u16* __restrict__ pre, const u16* __restrict__ projIU,
    const u16* __restrict__ projF,
    const float* __restrict__ ixb, const float* __restrict__ ihb,
    const float* __restrict__ uxb, const float* __restrict__ uhb,
    const float* __restrict__ fib, const float* __restrict__ fhb,
    u16* __restrict__ hb, float* __restrict__ c, float* __restrict__ out,
    int s, int crow0)
{
    const int nloc = blockIdx.x;
    const int j    = threadIdx.x;
    const int n    = s + nloc;

    const float aI = bf2f(pre[(size_t)n * 768 + j]) + ixb[j] + ihb[j]
                   + bf2f(projIU[(size_t)nloc * 512 + j]);
    const float aU = bf2f(pre[(size_t)n * 768 + 256 + j]) + uxb[j] + uhb[j]
                   + bf2f(projIU[(size_t)nloc * 512 + 256 + j]);
    const float fpre = bf2f(pre[(size_t)n * 768 + 512 + j]) + fib[j] + fhb[j];

    float fc = 0.f;
    #pragma unroll
    for (int k = 0; k < 4; ++k) {
        const float fg = sigm(fpre + bf2f(projF[(size_t)(4 * nloc + k) * 256 + j]));
        fc = fmaf(fg, c[(size_t)(crow0 + 4 * nloc + k) * HH + j], fc);
    }
    const float cn = fmaf(sigm(aI), ftanh(aU), fc);
    const float hn = ftanh(cn);
    hb[(size_t)n * HH + j] = f2bf(hn);
    c [(size_t)n * HH + j] = cn;
    if (n == 0) { out[j] = hn; out[HH + j] = cn; }
}

extern "C" void kernel_launch(void* const* d_in, const int* in_sizes, int n_in,
                              void* d_out, int out_size, void* d_ws, size_t ws_size,
                              hipStream_t stream) {
    const float* X   = (const float*)d_in[0];
    const float* ixw = (const float*)d_in[1];
    const float* ixb = (const float*)d_in[2];
    const float* ihw = (const float*)d_in[3];
    const float* ihb = (const float*)d_in[4];
    const float* uxw = (const float*)d_in[5];
    const float* uxb = (const float*)d_in[6];
    const float* uhw = (const float*)d_in[7];
    const float* uhb = (const float*)d_in[8];
    const float* fiw = (const float*)d_in[9];
    const float* fib = (const float*)d_in[10];
    const float* fhw = (const float*)d_in[11];
    const float* fhb = (const float*)d_in[12];
    float* out = (float*)d_out;

    char* ws = (char*)d_ws;
    u16*   hb   = (u16*)(ws + OFF_HB);
    float* cbuf = (float*)(ws + OFF_C);
    u16*   pre  = (u16*)(ws + OFF_PRE);
    u16*   Wxb  = (u16*)(ws + OFF_WXB);
    u16*   Whb  = (u16*)(ws + OFF_WHB);
    u16*   Xb   = (u16*)(ws + OFF_XB);
    u16*   pIU  = (u16*)(ws + OFF_PIU);
    u16*   pF   = (u16*)(ws + OFF_PF);

    conv_wx<<<480, 256, 0, stream>>>(ixw, uxw, fiw, (u32*)Wxb);
    conv_wh<<<384, 256, 0, stream>>>(ihw, uhw, fhw, (u32*)Whb, hb, cbuf);
    conv_x <<<2048, 256, 0, stream>>>(X, (u32*)Xb);

    leaf_gemm<<<dim3(384, 4), 256, 0, stream>>>(Xb, Wxb, ixb, ihb, uxb, uhb, hb, cbuf);
    proj_gemm<<<dim3(128, 6), 256, 0, stream>>>(Xb, Wxb, pre);

    const int starts[8] = {5461, 1365, 341, 85, 21, 5, 1, 0};
    const int ends[8]   = {16384, 5461, 1365, 341, 85, 21, 5, 1};
    for (int l = 0; l < 8; ++l) {
        const int s = starts[l], e = ends[l];
        const int L = e - s;
        const int crow0 = 4 * s + 1;
        const int nIUrb = (L + 127) >> 7;
        const int nFrb  = (4 * L + 127) >> 7;
        rec_gemm<<<nIUrb * 4 + nFrb * 2, 256, 0, stream>>>(hb, Whb, pIU, pF, crow0, L);
        gate_kernel<<<L, 256, 0, stream>>>(pre, pIU, pF,
            ixb, ihb, uxb, uhb, fib, fhb, hb, cbuf, out, s, crow0);
    }
}

// Round 9
// 220.477 us; speedup vs baseline: 1.1595x; 1.0567x over previous
//
#include <hip/hip_runtime.h>

// ChildSum TreeLSTM, complete 4-ary tree. N=65536, D=300(->320), H=256, K=4.
// Leaves = [16384,65536). Children of [s,e) are contiguous [4s+1,4e+1).
// Round 9: global_load_lds (16B) staging with pre-swizzled global source
// (linear LDS dest; source and read share the g^=(r&7) involution);
// c state stored bf16. hsum stays fused into rec_gemm IU A-staging (reg path).

#define NTOT 65536
#define DD   300
#define KP   320
#define HH   256
#define LEAF_START 16384

typedef unsigned short u16;
typedef unsigned int   u32;
typedef __attribute__((ext_vector_type(8))) short bf16x8;
typedef __attribute__((ext_vector_type(4))) float f32x4;

union BF8 { bf16x8 v; u16 u[8]; };

// ---- ws layout (bytes) ----
#define OFF_HB    0ull                                   // [65537][256] bf16
#define OFF_CB    33554944ull                            // [65537][256] bf16
#define OFF_PRE   67109888ull                            // [16384][768] bf16
#define OFF_WXB   92275712ull                            // [768][320] bf16
#define OFF_WHB   92767232ull                            // [768][256] bf16
#define OFF_XB    93160448ull                            // [65536][320] bf16
#define OFF_PIU   135103488ull                           // [11008][512] bf16
#define OFF_PF    146375680ull                           // [43776][256] bf16

__device__ __forceinline__ float sigm(float x) { return 1.f / (1.f + __expf(-x)); }
__device__ __forceinline__ float ftanh(float x) {
    x = fminf(15.f, fmaxf(-15.f, x));
    float e = __expf(2.f * x);
    return (e - 1.f) / (e + 1.f);
}
__device__ __forceinline__ u16 f2bf(float f) {
    union { float f; u32 u; } v; v.f = f;
    u32 r = v.u + 0x7fffu + ((v.u >> 16) & 1u);
    return (u16)(r >> 16);
}
__device__ __forceinline__ float bf2f(u16 b) {
    union { u32 u; float f; } v; v.u = ((u32)b) << 16;
    return v.f;
}
__device__ __forceinline__ int lidx(int r, int g) { return (r << 3) | (g ^ (r & 7)); }

// async global->LDS, 16B per lane; lds dest must be wave-linear (base+lane*16)
__device__ __forceinline__ void gll16(const void* g, void* l) {
    __builtin_amdgcn_global_load_lds(
        (const __attribute__((address_space(1))) unsigned int*)g,
        (__attribute__((address_space(3))) unsigned int*)l, 16, 0, 0);
}

// ---- X [N][300] f32 -> Xb [N][320] bf16 ----
__global__ __launch_bounds__(256) void conv_x(const float* __restrict__ X,
                                              u32* __restrict__ Xb2) {
    const size_t total = (size_t)NTOT * (KP / 2);
    for (size_t id = (size_t)blockIdx.x * 256 + threadIdx.x; id < total;
         id += (size_t)gridDim.x * 256) {
        const int node = (int)(id / (KP / 2));
        const int k    = ((int)(id % (KP / 2))) * 2;
        const float f0 = (k < DD)     ? X[(size_t)node * DD + k]     : 0.f;
        const float f1 = (k + 1 < DD) ? X[(size_t)node * DD + k + 1] : 0.f;
        Xb2[id] = (u32)f2bf(f0) | ((u32)f2bf(f1) << 16);
    }
}

// ---- stack [ixw; uxw; fiw] -> Wxb [768][320] bf16 ----
__global__ __launch_bounds__(256) void conv_wx(const float* __restrict__ ixw,
                                               const float* __restrict__ uxw,
                                               const float* __restrict__ fiw,
                                               u32* __restrict__ W2) {
    const int total = 768 * (KP / 2);
    for (int id = blockIdx.x * 256 + threadIdx.x; id < total;
         id += gridDim.x * 256) {
        const int row = id / (KP / 2);
        const int k   = (id % (KP / 2)) * 2;
        const float* src = (row < 256) ? (ixw + (size_t)row * DD)
                         : (row < 512) ? (uxw + (size_t)(row - 256) * DD)
                                       : (fiw + (size_t)(row - 512) * DD);
        const float f0 = (k < DD)     ? src[k]     : 0.f;
        const float f1 = (k + 1 < DD) ? src[k + 1] : 0.f;
        W2[id] = (u32)f2bf(f0) | ((u32)f2bf(f1) << 16);
    }
}

// ---- stack [ihw; uhw; fhw] -> Whb [768][256] bf16; block 0 zeroes pad row ----
__global__ __launch_bounds__(256) void conv_wh(const float* __restrict__ ihw,
                                               const float* __restrict__ uhw,
                                               const float* __restrict__ fhw,
                                               u32* __restrict__ W2,
                                               u16* __restrict__ hb,
                                               u16* __restrict__ cb) {
    if (blockIdx.x == 0) {
        const int t = threadIdx.x;
        hb[(size_t)NTOT * HH + t] = 0;
        cb[(size_t)NTOT * HH + t] = 0;
    }
    const int total = 768 * (HH / 2);
    for (int id = blockIdx.x * 256 + threadIdx.x; id < total;
         id += gridDim.x * 256) {
        const int row = id / (HH / 2);
        const int k   = (id % (HH / 2)) * 2;
        const float* src = (row < 256) ? (ihw + (size_t)row * HH)
                         : (row < 512) ? (uhw + (size_t)(row - 256) * HH)
                                       : (fhw + (size_t)(row - 512) * HH);
        W2[id] = (u32)f2bf(src[k]) | ((u32)f2bf(src[k + 1]) << 16);
    }
}

// ---- leaf GEMM: 128 nodes x 64 channels; B = [64 ix | 64 ux] same channels ----
__global__ __launch_bounds__(256) void leaf_gemm(
    const u16* __restrict__ Xb, const u16* __restrict__ Wxb,
    const float* __restrict__ ixb, const float* __restrict__ ihb,
    const float* __restrict__ uxb, const float* __restrict__ uhb,
    u16* __restrict__ hb, u16* __restrict__ cb)
{
    __shared__ bf16x8 Ash[1024];
    __shared__ bf16x8 Bsh[1024];

    const int tid  = threadIdx.x;
    const int lane = tid & 63;
    const int w    = tid >> 6;
    const int wr   = w >> 1, wc = w & 1;
    const int m16  = lane & 15, q = lane >> 4;

    const int row0   = LEAF_START + blockIdx.x * 128;
    const int chbase = blockIdx.y * 64;

    const bf16x8* __restrict__ Xv = (const bf16x8*)Xb;   // 40 granules/row
    const bf16x8* __restrict__ Wv = (const bf16x8*)Wxb;

    f32x4 accI[4][2], accU[4][2];
    #pragma unroll
    for (int mf = 0; mf < 4; ++mf)
        #pragma unroll
        for (int nf = 0; nf < 2; ++nf) { accI[mf][nf] = (f32x4)0.f; accU[mf][nf] = (f32x4)0.f; }

    for (int kt = 0; kt < 5; ++kt) {
        __syncthreads();
        #pragma unroll
        for (int i = 0; i < 4; ++i) {               // A: slots = linear, src pre-swizzled
            const int s = w * 256 + i * 64 + lane;
            const int r = s >> 3, gs = s & 7;
            const int g = gs ^ (r & 7);
            gll16(Xv + (size_t)(row0 + r) * 40 + kt * 8 + g, &Ash[s]);
        }
        #pragma unroll
        for (int i = 0; i < 4; ++i) {               // B: 0..63 ix, 64..127 ux
            const int s = w * 256 + i * 64 + lane;
            const int br = s >> 3, gs = s & 7;
            const int g = gs ^ (br & 7);
            const int srow = ((br >> 6) << 8) + chbase + (br & 63);
            gll16(Wv + (size_t)srow * 40 + kt * 8 + g, &Bsh[s]);
        }
        __syncthreads();

        #pragma unroll
        for (int ks = 0; ks < 2; ++ks) {
            const int kg = ks * 4 + q;
            bf16x8 a[4], bI[2], bU[2];
            #pragma unroll
            for (int mf = 0; mf < 4; ++mf)
                a[mf] = Ash[lidx(wr * 64 + mf * 16 + m16, kg)];
            #pragma unroll
            for (int nf = 0; nf < 2; ++nf) {
                bI[nf] = Bsh[lidx(wc * 32 + nf * 16 + m16, kg)];
                bU[nf] = Bsh[lidx(64 + wc * 32 + nf * 16 + m16, kg)];
            }
            #pragma unroll
            for (int mf = 0; mf < 4; ++mf)
                #pragma unroll
                for (int nf = 0; nf < 2; ++nf) {
                    accI[mf][nf] = __builtin_amdgcn_mfma_f32_16x16x32_bf16(
                        a[mf], bI[nf], accI[mf][nf], 0, 0, 0);
                    accU[mf][nf] = __builtin_amdgcn_mfma_f32_16x16x32_bf16(
                        a[mf], bU[nf], accU[mf][nf], 0, 0, 0);
                }
        }
    }

    #pragma unroll
    for (int nf = 0; nf < 2; ++nf) {
        const int ch = chbase + wc * 32 + nf * 16 + m16;
        const float bi = ixb[ch] + ihb[ch];   // recurrent biases apply at leaves
        const float bu = uxb[ch] + uhb[ch];
        #pragma unroll
        for (int mf = 0; mf < 4; ++mf) {
            #pragma unroll
            for (int r4 = 0; r4 < 4; ++r4) {
                const float cn = sigm(accI[mf][nf][r4] + bi) * ftanh(accU[mf][nf][r4] + bu);
                const int node = row0 + wr * 64 + mf * 16 + q * 4 + r4;
                const size_t off = (size_t)node * HH + ch;
                cb[off] = f2bf(cn);
                hb[off] = f2bf(ftanh(cn));
            }
        }
    }
}

// ---- input-proj GEMM: [16384 x 320] x [320 x 768] -> pre bf16 ----
__global__ __launch_bounds__(256) void proj_gemm(const u16* __restrict__ Xb,
                                                 const u16* __restrict__ Wxb,
                                                 u16* __restrict__ pre)
{
    __shared__ bf16x8 Ash[1024];
    __shared__ bf16x8 Bsh[1024];

    const int tid  = threadIdx.x;
    const int lane = tid & 63;
    const int w    = tid >> 6;
    const int wr   = w >> 1, wc = w & 1;
    const int m16  = lane & 15, q = lane >> 4;

    const int row0 = blockIdx.x * 128;
    const int n0   = blockIdx.y * 128;

    const bf16x8* __restrict__ Xv = (const bf16x8*)Xb;
    const bf16x8* __restrict__ Wv = (const bf16x8*)Wxb;

    f32x4 acc[4][4];
    #pragma unroll
    for (int mf = 0; mf < 4; ++mf)
        #pragma unroll
        for (int nf = 0; nf < 4; ++nf) acc[mf][nf] = (f32x4)0.f;

    for (int kt = 0; kt < 5; ++kt) {
        __syncthreads();
        #pragma unroll
        for (int i = 0; i < 4; ++i) {
            const int s = w * 256 + i * 64 + lane;
            const int r = s >> 3, gs = s & 7;
            const int g = gs ^ (r & 7);
            gll16(Xv + (size_t)(row0 + r) * 40 + kt * 8 + g, &Ash[s]);
        }
        #pragma unroll
        for (int i = 0; i < 4; ++i) {
            const int s = w * 256 + i * 64 + lane;
            const int br = s >> 3, gs = s & 7;
            const int g = gs ^ (br & 7);
            gll16(Wv + (size_t)(n0 + br) * 40 + kt * 8 + g, &Bsh[s]);
        }
        __syncthreads();

        #pragma unroll
        for (int ks = 0; ks < 2; ++ks) {
            const int kg = ks * 4 + q;
            bf16x8 a[4], b[4];
            #pragma unroll
            for (int mf = 0; mf < 4; ++mf)
                a[mf] = Ash[lidx(wr * 64 + mf * 16 + m16, kg)];
            #pragma unroll
            for (int nf = 0; nf < 4; ++nf)
                b[nf] = Bsh[lidx(wc * 64 + nf * 16 + m16, kg)];
            #pragma unroll
            for (int mf = 0; mf < 4; ++mf)
                #pragma unroll
                for (int nf = 0; nf < 4; ++nf)
                    acc[mf][nf] = __builtin_amdgcn_mfma_f32_16x16x32_bf16(
                        a[mf], b[nf], acc[mf][nf], 0, 0, 0);
        }
    }

    #pragma unroll
    for (int mf = 0; mf < 4; ++mf)
        #pragma unroll
        for (int nf = 0; nf < 4; ++nf) {
            const int col = n0 + wc * 64 + nf * 16 + m16;
            #pragma unroll
            for (int r4 = 0; r4 < 4; ++r4) {
                const int node = row0 + wr * 64 + mf * 16 + q * 4 + r4;
                pre[(size_t)node * 768 + col] = f2bf(acc[mf][nf][r4]);
            }
        }
}

// ---- per-level recurrent GEMM; hsum computed in A-staging (IU path) ----
__global__ __launch_bounds__(256) void rec_gemm(const u16* __restrict__ hb,
                                                const u16* __restrict__ Whb,
                                                u16* __restrict__ projIU,
                                                u16* __restrict__ projF,
                                                int crow0, int L)
{
    __shared__ bf16x8 Ash[1024];
    __shared__ bf16x8 Bsh[1024];

    const int nIUrb = (L + 127) >> 7;
    const int bid   = blockIdx.x;

    bool isIU; int rb, cb_;
    if (bid < nIUrb * 4) { isIU = true;  rb = bid >> 2; cb_ = bid & 3; }
    else { isIU = false; const int b2 = bid - nIUrb * 4; rb = b2 >> 1; cb_ = b2 & 1; }

    const int row0  = rb * 128;
    const int Brow0 = isIU ? cb_ * 128 : 512 + cb_ * 128;
    const int ocol0 = cb_ * 128;
    u16* __restrict__ out = isIU ? projIU : projF;
    const int ostride = isIU ? 512 : 256;

    const int tid  = threadIdx.x;
    const int lane = tid & 63;
    const int w    = tid >> 6;
    const int wr   = w >> 1, wc = w & 1;
    const int m16  = lane & 15, q = lane >> 4;

    const bf16x8* __restrict__ Hv = (const bf16x8*)hb;   // 32 granules/row
    const bf16x8* __restrict__ Wv = (const bf16x8*)Whb;

    f32x4 acc[4][4];
    #pragma unroll
    for (int mf = 0; mf < 4; ++mf)
        #pragma unroll
        for (int nf = 0; nf < 4; ++nf) acc[mf][nf] = (f32x4)0.f;

    for (int kt = 0; kt < 4; ++kt) {
        __syncthreads();
        if (isIU) {
            #pragma unroll
            for (int i = 0; i < 4; ++i) {            // reg-staged hsum
                const int G = tid + i * 256;
                const int r = G >> 3, g = G & 7;
                bf16x8 val;
                if (row0 + r < L) {
                    const size_t cg0 = (size_t)(crow0 + 4 * (row0 + r)) * 32 + kt * 8 + g;
                    BF8 x0, x1, x2, x3, o;
                    x0.v = Hv[cg0]; x1.v = Hv[cg0 + 32];
                    x2.v = Hv[cg0 + 64]; x3.v = Hv[cg0 + 96];
                    #pragma unroll
                    for (int j = 0; j < 8; ++j)
                        o.u[j] = f2bf(bf2f(x0.u[j]) + bf2f(x1.u[j])
                                    + bf2f(x2.u[j]) + bf2f(x3.u[j]));
                    val = o.v;
                } else {
                    BF8 z;
                    #pragma unroll
                    for (int j = 0; j < 8; ++j) z.u[j] = 0;
                    val = z.v;
                }
                Ash[lidx(r, g)] = val;
            }
        } else {
            #pragma unroll
            for (int i = 0; i < 4; ++i) {            // direct-to-LDS child rows
                const int s = w * 256 + i * 64 + lane;
                const int r = s >> 3, gs = s & 7;
                const int g = gs ^ (r & 7);
                int srow = crow0 + row0 + r;
                if (srow > NTOT) srow = NTOT;        // zeroed pad row
                gll16(Hv + (size_t)srow * 32 + kt * 8 + g, &Ash[s]);
            }
        }
        #pragma unroll
        for (int i = 0; i < 4; ++i) {
            const int s = w * 256 + i * 64 + lane;
            const int br = s >> 3, gs = s & 7;
            const int g = gs ^ (br & 7);
            gll16(Wv + (size_t)(Brow0 + br) * 32 + kt * 8 + g, &Bsh[s]);
        }
        __syncthreads();

        #pragma unroll
        for (int ks = 0; ks < 2; ++ks) {
            const int kg = ks * 4 + q;
            bf16x8 a[4], b[4];
            #pragma unroll
            for (int mf = 0; mf < 4; ++mf)
                a[mf] = Ash[lidx(wr * 64 + mf * 16 + m16, kg)];
            #pragma unroll
            for (int nf = 0; nf < 4; ++nf)
                b[nf] = Bsh[lidx(wc * 64 + nf * 16 + m16, kg)];
            #pragma unroll
            for (int mf = 0; mf < 4; ++mf)
                #pragma unroll
                for (int nf = 0; nf < 4; ++nf)
                    acc[mf][nf] = __builtin_amdgcn_mfma_f32_16x16x32_bf16(
                        a[mf], b[nf], acc[mf][nf], 0, 0, 0);
        }
    }

    #pragma unroll
    for (int mf = 0; mf < 4; ++mf)
        #pragma unroll
        for (int nf = 0; nf < 4; ++nf) {
            const int col = ocol0 + wc * 64 + nf * 16 + m16;
            #pragma unroll
            for (int r4 = 0; r4 < 4; ++r4) {
                const int orow = row0 + wr * 64 + mf * 16 + q * 4 + r4;
                out[(size_t)orow * ostride + col] = f2bf(acc[mf][nf][r4]);
            }
        }
}

// ---- per-level gates (f32 math, bf16 c state) ----
__global__ __launch_bounds__(256) void gate_kernel(
    const u16* __restrict__ pre, const u16* __restrict__ projIU,
    const u16* __restrict__ projF,
    const float* __restrict__ ixb, const float* __restrict__ ihb,
    const float* __restrict__ uxb, const float* __restrict__ uhb,
    const float* __restrict__ fib, const float* __restrict__ fhb,
    u16* __restrict__ hb, u16* __restrict__ cb, float* __restrict__ out,
    int s, int crow0)
{
    const int nloc = blockIdx.x;
    const int j    = threadIdx.x;
    const int n    = s + nloc;

    const float aI = bf2f(pre[(size_t)n * 768 + j]) + ixb[j] + ihb[j]
                   + bf2f(projIU[(size_t)nloc * 512 + j]);
    const float aU = bf2f(pre[(size_t)n * 768 + 256 + j]) + uxb[j] + uhb[j]
                   + bf2f(projIU[(size_t)nloc * 512 + 256 + j]);
    const float fpre = bf2f(pre[(size_t)n * 768 + 512 + j]) + fib[j] + fhb[j];

    float fc = 0.f;
    #pragma unroll
    for (int k = 0; k < 4; ++k) {
        const float fg = sigm(fpre + bf2f(projF[(size_t)(4 * nloc + k) * 256 + j]));
        const float cc = bf2f(cb[(size_t)(crow0 + 4 * nloc + k) * HH + j]);
        fc = fmaf(fg, cc, fc);
    }
    const float cn = fmaf(sigm(aI), ftanh(aU), fc);
    const float hn = ftanh(cn);
    hb[(size_t)n * HH + j] = f2bf(hn);
    cb[(size_t)n * HH + j] = f2bf(cn);
    if (n == 0) { out[j] = hn; out[HH + j] = cn; }
}

extern "C" void kernel_launch(void* const* d_in, const int* in_sizes, int n_in,
                              void* d_out, int out_size, void* d_ws, size_t ws_size,
                              hipStream_t stream) {
    const float* X   = (const float*)d_in[0];
    const float* ixw = (const float*)d_in[1];
    const float* ixb = (const float*)d_in[2];
    const float* ihw = (const float*)d_in[3];
    const float* ihb = (const float*)d_in[4];
    const float* uxw = (const float*)d_in[5];
    const float* uxb = (const float*)d_in[6];
    const float* uhw = (const float*)d_in[7];
    const float* uhb = (const float*)d_in[8];
    const float* fiw = (const float*)d_in[9];
    const float* fib = (const float*)d_in[10];
    const float* fhw = (const float*)d_in[11];
    const float* fhb = (const float*)d_in[12];
    float* out = (float*)d_out;

    char* ws = (char*)d_ws;
    u16* hb  = (u16*)(ws + OFF_HB);
    u16* cb  = (u16*)(ws + OFF_CB);
    u16* pre = (u16*)(ws + OFF_PRE);
    u16* Wxb = (u16*)(ws + OFF_WXB);
    u16* Whb = (u16*)(ws + OFF_WHB);
    u16* Xb  = (u16*)(ws + OFF_XB);
    u16* pIU = (u16*)(ws + OFF_PIU);
    u16* pF  = (u16*)(ws + OFF_PF);

    conv_wx<<<480, 256, 0, stream>>>(ixw, uxw, fiw, (u32*)Wxb);
    conv_wh<<<384, 256, 0, stream>>>(ihw, uhw, fhw, (u32*)Whb, hb, cb);
    conv_x <<<2048, 256, 0, stream>>>(X, (u32*)Xb);

    leaf_gemm<<<dim3(384, 4), 256, 0, stream>>>(Xb, Wxb, ixb, ihb, uxb, uhb, hb, cb);
    proj_gemm<<<dim3(128, 6), 256, 0, stream>>>(Xb, Wxb, pre);

    const int starts[8] = {5461, 1365, 341, 85, 21, 5, 1, 0};
    const int ends[8]   = {16384, 5461, 1365, 341, 85, 21, 5, 1};
    for (int l = 0; l < 8; ++l) {
        const int s = starts[l], e = ends[l];
        const int L = e - s;
        const int crow0 = 4 * s + 1;
        const int nIUrb = (L + 127) >> 7;
        const int nFrb  = (4 * L + 127) >> 7;
        rec_gemm<<<nIUrb * 4 + nFrb * 2, 256, 0, stream>>>(hb, Whb, pIU, pF, crow0, L);
        gate_kernel<<<L, 256, 0, stream>>>(pre, pIU, pF,
            ixb, ihb, uxb, uhb, fib, fhb, hb, cb, out, s, crow0);
    }
}

// Round 10
// 213.228 us; speedup vs baseline: 1.1990x; 1.0340x over previous
//
#include <hip/hip_runtime.h>
#include <hip/hip_bf16.h>

// ChildSum TreeLSTM, complete 4-ary tree. N=65536, D=300(->320), H=256, K=4.
// Leaves = [16384,65536). Children of [s,e) are contiguous [4s+1,4e+1).
// Round 10: fast activations (exp2/rcp), HW bf16 cvt everywhere, vectorized
// gate kernel (u32 loads, 2 nodes/block), combined bias tables.

#define NTOT 65536
#define DD   300
#define KP   320
#define HH   256
#define LEAF_START 16384
#define LOG2E 1.4426950408889634f

typedef unsigned short u16;
typedef unsigned int   u32;
typedef __attribute__((ext_vector_type(8))) short bf16x8;
typedef __attribute__((ext_vector_type(4))) float f32x4;

union BF8 { bf16x8 v; u16 u[8]; };

// ---- ws layout (bytes) ----
#define OFF_HB    0ull                                   // [65537][256] bf16
#define OFF_CB    33554944ull                            // [65537][256] bf16
#define OFF_PRE   67109888ull                            // [16384][768] bf16
#define OFF_WXB   92275712ull                            // [768][320] bf16
#define OFF_WHB   92767232ull                            // [768][256] bf16
#define OFF_XB    93160448ull                            // [65536][320] bf16
#define OFF_PIU   135103488ull                           // [11008][512] bf16
#define OFF_PF    146375680ull                           // [43776][256] bf16
#define OFF_BI    168788992ull                           // [256] f32 (ixb+ihb)
#define OFF_BU    168790016ull                           // [256] f32
#define OFF_BF    168791040ull                           // [256] f32

__device__ __forceinline__ float frcp(float x) { return __builtin_amdgcn_rcpf(x); }
__device__ __forceinline__ float fex2(float x) { return __builtin_amdgcn_exp2f(x); }
// sigmoid: 1/(1+2^(-x*log2e))   tanh: 1-2/(1+2^(2x*log2e))  (saturation-safe)
__device__ __forceinline__ float sigm(float x)  { return frcp(1.f + fex2(-LOG2E * x)); }
__device__ __forceinline__ float ftanh(float x) { return 1.f - 2.f * frcp(1.f + fex2(2.f * LOG2E * x)); }

__device__ __forceinline__ u16 f2bf(float f) {           // HW RNE convert
    __hip_bfloat16 b = __float2bfloat16(f);
    u16 u; __builtin_memcpy(&u, &b, 2); return u;
}
__device__ __forceinline__ float bf2f(u16 b) {
    union { u32 u; float f; } v; v.u = ((u32)b) << 16;
    return v.f;
}
__device__ __forceinline__ int lidx(int r, int g) { return (r << 3) | (g ^ (r & 7)); }

// async global->LDS, 16B per lane; lds dest wave-linear
__device__ __forceinline__ void gll16(const void* g, void* l) {
    __builtin_amdgcn_global_load_lds(
        (const __attribute__((address_space(1))) unsigned int*)g,
        (__attribute__((address_space(3))) unsigned int*)l, 16, 0, 0);
}

// ---- X [N][300] f32 -> Xb [N][320] bf16 ----
__global__ __launch_bounds__(256) void conv_x(const float* __restrict__ X,
                                              u32* __restrict__ Xb2) {
    const size_t total = (size_t)NTOT * (KP / 2);
    for (size_t id = (size_t)blockIdx.x * 256 + threadIdx.x; id < total;
         id += (size_t)gridDim.x * 256) {
        const int node = (int)(id / (KP / 2));
        const int k    = ((int)(id % (KP / 2))) * 2;
        const float f0 = (k < DD)     ? X[(size_t)node * DD + k]     : 0.f;
        const float f1 = (k + 1 < DD) ? X[(size_t)node * DD + k + 1] : 0.f;
        Xb2[id] = (u32)f2bf(f0) | ((u32)f2bf(f1) << 16);
    }
}

// ---- stack [ixw; uxw; fiw] -> Wxb [768][320] bf16 ----
__global__ __launch_bounds__(256) void conv_wx(const float* __restrict__ ixw,
                                               const float* __restrict__ uxw,
                                               const float* __restrict__ fiw,
                                               u32* __restrict__ W2) {
    const int total = 768 * (KP / 2);
    for (int id = blockIdx.x * 256 + threadIdx.x; id < total;
         id += gridDim.x * 256) {
        const int row = id / (KP / 2);
        const int k   = (id % (KP / 2)) * 2;
        const float* src = (row < 256) ? (ixw + (size_t)row * DD)
                         : (row < 512) ? (uxw + (size_t)(row - 256) * DD)
                                       : (fiw + (size_t)(row - 512) * DD);
        const float f0 = (k < DD)     ? src[k]     : 0.f;
        const float f1 = (k + 1 < DD) ? src[k + 1] : 0.f;
        W2[id] = (u32)f2bf(f0) | ((u32)f2bf(f1) << 16);
    }
}

// ---- stack [ihw; uhw; fhw] -> Whb; block0: pad rows + combined biases ----
__global__ __launch_bounds__(256) void conv_wh(const float* __restrict__ ihw,
                                               const float* __restrict__ uhw,
                                               const float* __restrict__ fhw,
                                               const float* __restrict__ ixb,
                                               const float* __restrict__ ihb,
                                               const float* __restrict__ uxb,
                                               const float* __restrict__ uhb,
                                               const float* __restrict__ fib,
                                               const float* __restrict__ fhb,
                                               u32* __restrict__ W2,
                                               u16* __restrict__ hb,
                                               u16* __restrict__ cb,
                                               float* __restrict__ bI,
                                               float* __restrict__ bU,
                                               float* __restrict__ bF) {
    if (blockIdx.x == 0) {
        const int t = threadIdx.x;
        hb[(size_t)NTOT * HH + t] = 0;
        cb[(size_t)NTOT * HH + t] = 0;
        bI[t] = ixb[t] + ihb[t];
        bU[t] = uxb[t] + uhb[t];
        bF[t] = fib[t] + fhb[t];
    }
    const int total = 768 * (HH / 2);
    for (int id = blockIdx.x * 256 + threadIdx.x; id < total;
         id += gridDim.x * 256) {
        const int row = id / (HH / 2);
        const int k   = (id % (HH / 2)) * 2;
        const float* src = (row < 256) ? (ihw + (size_t)row * HH)
                         : (row < 512) ? (uhw + (size_t)(row - 256) * HH)
                                       : (fhw + (size_t)(row - 512) * HH);
        W2[id] = (u32)f2bf(src[k]) | ((u32)f2bf(src[k + 1]) << 16);
    }
}

// ---- leaf GEMM: 128 nodes x 64 channels; B = [64 ix | 64 ux] same channels ----
__global__ __launch_bounds__(256) void leaf_gemm(
    const u16* __restrict__ Xb, const u16* __restrict__ Wxb,
    const float* __restrict__ bI, const float* __restrict__ bU,
    u16* __restrict__ hb, u16* __restrict__ cb)
{
    __shared__ bf16x8 Ash[1024];
    __shared__ bf16x8 Bsh[1024];

    const int tid  = threadIdx.x;
    const int lane = tid & 63;
    const int w    = tid >> 6;
    const int wr   = w >> 1, wc = w & 1;
    const int m16  = lane & 15, q = lane >> 4;

    const int row0   = LEAF_START + blockIdx.x * 128;
    const int chbase = blockIdx.y * 64;

    const bf16x8* __restrict__ Xv = (const bf16x8*)Xb;   // 40 granules/row
    const bf16x8* __restrict__ Wv = (const bf16x8*)Wxb;

    f32x4 accI[4][2], accU[4][2];
    #pragma unroll
    for (int mf = 0; mf < 4; ++mf)
        #pragma unroll
        for (int nf = 0; nf < 2; ++nf) { accI[mf][nf] = (f32x4)0.f; accU[mf][nf] = (f32x4)0.f; }

    for (int kt = 0; kt < 5; ++kt) {
        __syncthreads();
        #pragma unroll
        for (int i = 0; i < 4; ++i) {               // A: linear dest, pre-swizzled src
            const int s = w * 256 + i * 64 + lane;
            const int r = s >> 3, gs = s & 7;
            const int g = gs ^ (r & 7);
            gll16(Xv + (size_t)(row0 + r) * 40 + kt * 8 + g, &Ash[s]);
        }
        #pragma unroll
        for (int i = 0; i < 4; ++i) {               // B: 0..63 ix, 64..127 ux
            const int s = w * 256 + i * 64 + lane;
            const int br = s >> 3, gs = s & 7;
            const int g = gs ^ (br & 7);
            const int srow = ((br >> 6) << 8) + chbase + (br & 63);
            gll16(Wv + (size_t)srow * 40 + kt * 8 + g, &Bsh[s]);
        }
        __syncthreads();

        #pragma unroll
        for (int ks = 0; ks < 2; ++ks) {
            const int kg = ks * 4 + q;
            bf16x8 a[4], bIv[2], bUv[2];
            #pragma unroll
            for (int mf = 0; mf < 4; ++mf)
                a[mf] = Ash[lidx(wr * 64 + mf * 16 + m16, kg)];
            #pragma unroll
            for (int nf = 0; nf < 2; ++nf) {
                bIv[nf] = Bsh[lidx(wc * 32 + nf * 16 + m16, kg)];
                bUv[nf] = Bsh[lidx(64 + wc * 32 + nf * 16 + m16, kg)];
            }
            #pragma unroll
            for (int mf = 0; mf < 4; ++mf)
                #pragma unroll
                for (int nf = 0; nf < 2; ++nf) {
                    accI[mf][nf] = __builtin_amdgcn_mfma_f32_16x16x32_bf16(
                        a[mf], bIv[nf], accI[mf][nf], 0, 0, 0);
                    accU[mf][nf] = __builtin_amdgcn_mfma_f32_16x16x32_bf16(
                        a[mf], bUv[nf], accU[mf][nf], 0, 0, 0);
                }
        }
    }

    #pragma unroll
    for (int nf = 0; nf < 2; ++nf) {
        const int ch = chbase + wc * 32 + nf * 16 + m16;
        const float bi = bI[ch];                   // combined ixb+ihb (leaves too)
        const float bu = bU[ch];
        #pragma unroll
        for (int mf = 0; mf < 4; ++mf) {
            #pragma unroll
            for (int r4 = 0; r4 < 4; ++r4) {
                const float cn = sigm(accI[mf][nf][r4] + bi) * ftanh(accU[mf][nf][r4] + bu);
                const int node = row0 + wr * 64 + mf * 16 + q * 4 + r4;
                const size_t off = (size_t)node * HH + ch;
                cb[off] = f2bf(cn);
                hb[off] = f2bf(ftanh(cn));
            }
        }
    }
}

// ---- input-proj GEMM: [16384 x 320] x [320 x 768] -> pre bf16 ----
__global__ __launch_bounds__(256) void proj_gemm(const u16* __restrict__ Xb,
                                                 const u16* __restrict__ Wxb,
                                                 u16* __restrict__ pre)
{
    __shared__ bf16x8 Ash[1024];
    __shared__ bf16x8 Bsh[1024];

    const int tid  = threadIdx.x;
    const int lane = tid & 63;
    const int w    = tid >> 6;
    const int wr   = w >> 1, wc = w & 1;
    const int m16  = lane & 15, q = lane >> 4;

    const int row0 = blockIdx.x * 128;
    const int n0   = blockIdx.y * 128;

    const bf16x8* __restrict__ Xv = (const bf16x8*)Xb;
    const bf16x8* __restrict__ Wv = (const bf16x8*)Wxb;

    f32x4 acc[4][4];
    #pragma unroll
    for (int mf = 0; mf < 4; ++mf)
        #pragma unroll
        for (int nf = 0; nf < 4; ++nf) acc[mf][nf] = (f32x4)0.f;

    for (int kt = 0; kt < 5; ++kt) {
        __syncthreads();
        #pragma unroll
        for (int i = 0; i < 4; ++i) {
            const int s = w * 256 + i * 64 + lane;
            const int r = s >> 3, gs = s & 7;
            const int g = gs ^ (r & 7);
            gll16(Xv + (size_t)(row0 + r) * 40 + kt * 8 + g, &Ash[s]);
        }
        #pragma unroll
        for (int i = 0; i < 4; ++i) {
            const int s = w * 256 + i * 64 + lane;
            const int br = s >> 3, gs = s & 7;
            const int g = gs ^ (br & 7);
            gll16(Wv + (size_t)(n0 + br) * 40 + kt * 8 + g, &Bsh[s]);
        }
        __syncthreads();

        #pragma unroll
        for (int ks = 0; ks < 2; ++ks) {
            const int kg = ks * 4 + q;
            bf16x8 a[4], b[4];
            #pragma unroll
            for (int mf = 0; mf < 4; ++mf)
                a[mf] = Ash[lidx(wr * 64 + mf * 16 + m16, kg)];
            #pragma unroll
            for (int nf = 0; nf < 4; ++nf)
                b[nf] = Bsh[lidx(wc * 64 + nf * 16 + m16, kg)];
            #pragma unroll
            for (int mf = 0; mf < 4; ++mf)
                #pragma unroll
                for (int nf = 0; nf < 4; ++nf)
                    acc[mf][nf] = __builtin_amdgcn_mfma_f32_16x16x32_bf16(
                        a[mf], b[nf], acc[mf][nf], 0, 0, 0);
        }
    }

    #pragma unroll
    for (int mf = 0; mf < 4; ++mf)
        #pragma unroll
        for (int nf = 0; nf < 4; ++nf) {
            const int col = n0 + wc * 64 + nf * 16 + m16;
            #pragma unroll
            for (int r4 = 0; r4 < 4; ++r4) {
                const int node = row0 + wr * 64 + mf * 16 + q * 4 + r4;
                pre[(size_t)node * 768 + col] = f2bf(acc[mf][nf][r4]);
            }
        }
}

// ---- per-level recurrent GEMM; hsum computed in A-staging (IU path) ----
__global__ __launch_bounds__(256) void rec_gemm(const u16* __restrict__ hb,
                                                const u16* __restrict__ Whb,
                                                u16* __restrict__ projIU,
                                                u16* __restrict__ projF,
                                                int crow0, int L)
{
    __shared__ bf16x8 Ash[1024];
    __shared__ bf16x8 Bsh[1024];

    const int nIUrb = (L + 127) >> 7;
    const int bid   = blockIdx.x;

    bool isIU; int rb, cb_;
    if (bid < nIUrb * 4) { isIU = true;  rb = bid >> 2; cb_ = bid & 3; }
    else { isIU = false; const int b2 = bid - nIUrb * 4; rb = b2 >> 1; cb_ = b2 & 1; }

    const int row0  = rb * 128;
    const int Brow0 = isIU ? cb_ * 128 : 512 + cb_ * 128;
    const int ocol0 = cb_ * 128;
    u16* __restrict__ out = isIU ? projIU : projF;
    const int ostride = isIU ? 512 : 256;

    const int tid  = threadIdx.x;
    const int lane = tid & 63;
    const int w    = tid >> 6;
    const int wr   = w >> 1, wc = w & 1;
    const int m16  = lane & 15, q = lane >> 4;

    const bf16x8* __restrict__ Hv = (const bf16x8*)hb;   // 32 granules/row
    const bf16x8* __restrict__ Wv = (const bf16x8*)Whb;

    f32x4 acc[4][4];
    #pragma unroll
    for (int mf = 0; mf < 4; ++mf)
        #pragma unroll
        for (int nf = 0; nf < 4; ++nf) acc[mf][nf] = (f32x4)0.f;

    for (int kt = 0; kt < 4; ++kt) {
        __syncthreads();
        if (isIU) {
            #pragma unroll
            for (int i = 0; i < 4; ++i) {            // reg-staged hsum
                const int G = tid + i * 256;
                const int r = G >> 3, g = G & 7;
                bf16x8 val;
                if (row0 + r < L) {
                    const size_t cg0 = (size_t)(crow0 + 4 * (row0 + r)) * 32 + kt * 8 + g;
                    BF8 x0, x1, x2, x3, o;
                    x0.v = Hv[cg0]; x1.v = Hv[cg0 + 32];
                    x2.v = Hv[cg0 + 64]; x3.v = Hv[cg0 + 96];
                    #pragma unroll
                    for (int j = 0; j < 8; ++j)
                        o.u[j] = f2bf(bf2f(x0.u[j]) + bf2f(x1.u[j])
                                    + bf2f(x2.u[j]) + bf2f(x3.u[j]));
                    val = o.v;
                } else {
                    BF8 z;
                    #pragma unroll
                    for (int j = 0; j < 8; ++j) z.u[j] = 0;
                    val = z.v;
                }
                Ash[lidx(r, g)] = val;
            }
        } else {
            #pragma unroll
            for (int i = 0; i < 4; ++i) {            // direct-to-LDS child rows
                const int s = w * 256 + i * 64 + lane;
                const int r = s >> 3, gs = s & 7;
                const int g = gs ^ (r & 7);
                int srow = crow0 + row0 + r;
                if (srow > NTOT) srow = NTOT;        // zeroed pad row
                gll16(Hv + (size_t)srow * 32 + kt * 8 + g, &Ash[s]);
            }
        }
        #pragma unroll
        for (int i = 0; i < 4; ++i) {
            const int s = w * 256 + i * 64 + lane;
            const int br = s >> 3, gs = s & 7;
            const int g = gs ^ (br & 7);
            gll16(Wv + (size_t)(Brow0 + br) * 32 + kt * 8 + g, &Bsh[s]);
        }
        __syncthreads();

        #pragma unroll
        for (int ks = 0; ks < 2; ++ks) {
            const int kg = ks * 4 + q;
            bf16x8 a[4], b[4];
            #pragma unroll
            for (int mf = 0; mf < 4; ++mf)
                a[mf] = Ash[lidx(wr * 64 + mf * 16 + m16, kg)];
            #pragma unroll
            for (int nf = 0; nf < 4; ++nf)
                b[nf] = Bsh[lidx(wc * 64 + nf * 16 + m16, kg)];
            #pragma unroll
            for (int mf = 0; mf < 4; ++mf)
                #pragma unroll
                for (int nf = 0; nf < 4; ++nf)
                    acc[mf][nf] = __builtin_amdgcn_mfma_f32_16x16x32_bf16(
                        a[mf], b[nf], acc[mf][nf], 0, 0, 0);
        }
    }

    #pragma unroll
    for (int mf = 0; mf < 4; ++mf)
        #pragma unroll
        for (int nf = 0; nf < 4; ++nf) {
            const int col = ocol0 + wc * 64 + nf * 16 + m16;
            #pragma unroll
            for (int r4 = 0; r4 < 4; ++r4) {
                const int orow = row0 + wr * 64 + mf * 16 + q * 4 + r4;
                out[(size_t)orow * ostride + col] = f2bf(acc[mf][nf][r4]);
            }
        }
}

// ---- per-level gates: 2 nodes/block, u32 (2-channel) per thread ----
__global__ __launch_bounds__(256) void gate_kernel(
    const u32* __restrict__ pre2, const u32* __restrict__ pIU2,
    const u32* __restrict__ pF2,
    const float* __restrict__ bI, const float* __restrict__ bU,
    const float* __restrict__ bF,
    u32* __restrict__ hb2, u32* __restrict__ cb2, float* __restrict__ out,
    int s, int crow0, int L)
{
    const int t    = threadIdx.x;
    const int half = t >> 7;
    const int j2   = t & 127;                 // u32 index: channels 2j2, 2j2+1
    const int nloc = blockIdx.x * 2 + half;
    if (nloc >= L) return;
    const int n = s + nloc;

    const u32 pi = pre2[(size_t)n * 384 + j2];
    const u32 pu = pre2[(size_t)n * 384 + 128 + j2];
    const u32 pf = pre2[(size_t)n * 384 + 256 + j2];
    const u32 ri = pIU2[(size_t)nloc * 256 + j2];
    const u32 ru = pIU2[(size_t)nloc * 256 + 128 + j2];
    const float2 vbi = ((const float2*)bI)[j2];
    const float2 vbu = ((const float2*)bU)[j2];
    const float2 vbf = ((const float2*)bF)[j2];

    const float aI0 = bf2f((u16)pi) + bf2f((u16)ri) + vbi.x;
    const float aI1 = bf2f((u16)(pi >> 16)) + bf2f((u16)(ri >> 16)) + vbi.y;
    const float aU0 = bf2f((u16)pu) + bf2f((u16)ru) + vbu.x;
    const float aU1 = bf2f((u16)(pu >> 16)) + bf2f((u16)(ru >> 16)) + vbu.y;
    const float fp0 = bf2f((u16)pf) + vbf.x;
    const float fp1 = bf2f((u16)(pf >> 16)) + vbf.y;

    float fc0 = 0.f, fc1 = 0.f;
    #pragma unroll
    for (int k = 0; k < 4; ++k) {
        const u32 rf = pF2[(size_t)(4 * nloc + k) * 128 + j2];
        const u32 cc = cb2[(size_t)(crow0 + 4 * nloc + k) * 128 + j2];
        fc0 = fmaf(sigm(fp0 + bf2f((u16)rf)), bf2f((u16)cc), fc0);
        fc1 = fmaf(sigm(fp1 + bf2f((u16)(rf >> 16))), bf2f((u16)(cc >> 16)), fc1);
    }
    const float cn0 = fmaf(sigm(aI0), ftanh(aU0), fc0);
    const float cn1 = fmaf(sigm(aI1), ftanh(aU1), fc1);
    const float hn0 = ftanh(cn0);
    const float hn1 = ftanh(cn1);
    hb2[(size_t)n * 128 + j2] = (u32)f2bf(hn0) | ((u32)f2bf(hn1) << 16);
    cb2[(size_t)n * 128 + j2] = (u32)f2bf(cn0) | ((u32)f2bf(cn1) << 16);
    if (n == 0) {
        ((float2*)out)[j2] = make_float2(hn0, hn1);
        ((float2*)(out + 256))[j2] = make_float2(cn0, cn1);
    }
}

extern "C" void kernel_launch(void* const* d_in, const int* in_sizes, int n_in,
                              void* d_out, int out_size, void* d_ws, size_t ws_size,
                              hipStream_t stream) {
    const float* X   = (const float*)d_in[0];
    const float* ixw = (const float*)d_in[1];
    const float* ixb = (const float*)d_in[2];
    const float* ihw = (const float*)d_in[3];
    const float* ihb = (const float*)d_in[4];
    const float* uxw = (const float*)d_in[5];
    const float* uxb = (const float*)d_in[6];
    const float* uhw = (const float*)d_in[7];
    const float* uhb = (const float*)d_in[8];
    const float* fiw = (const float*)d_in[9];
    const float* fib = (const float*)d_in[10];
    const float* fhw = (const float*)d_in[11];
    const float* fhb = (const float*)d_in[12];
    float* out = (float*)d_out;

    char* ws = (char*)d_ws;
    u16* hb  = (u16*)(ws + OFF_HB);
    u16* cb  = (u16*)(ws + OFF_CB);
    u16* pre = (u16*)(ws + OFF_PRE);
    u16* Wxb = (u16*)(ws + OFF_WXB);
    u16* Whb = (u16*)(ws + OFF_WHB);
    u16* Xb  = (u16*)(ws + OFF_XB);
    u16* pIU = (u16*)(ws + OFF_PIU);
    u16* pF  = (u16*)(ws + OFF_PF);
    float* bI = (float*)(ws + OFF_BI);
    float* bU = (float*)(ws + OFF_BU);
    float* bF = (float*)(ws + OFF_BF);

    conv_wx<<<480, 256, 0, stream>>>(ixw, uxw, fiw, (u32*)Wxb);
    conv_wh<<<384, 256, 0, stream>>>(ihw, uhw, fhw, ixb, ihb, uxb, uhb, fib, fhb,
                                     (u32*)Whb, hb, cb, bI, bU, bF);
    conv_x <<<2048, 256, 0, stream>>>(X, (u32*)Xb);

    leaf_gemm<<<dim3(384, 4), 256, 0, stream>>>(Xb, Wxb, bI, bU, hb, cb);
    proj_gemm<<<dim3(128, 6), 256, 0, stream>>>(Xb, Wxb, pre);

    const int starts[8] = {5461, 1365, 341, 85, 21, 5, 1, 0};
    const int ends[8]   = {16384, 5461, 1365, 341, 85, 21, 5, 1};
    for (int l = 0; l < 8; ++l) {
        const int s = starts[l], e = ends[l];
        const int L = e - s;
        const int crow0 = 4 * s + 1;
        const int nIUrb = (L + 127) >> 7;
        const int nFrb  = (4 * L + 127) >> 7;
        rec_gemm<<<nIUrb * 4 + nFrb * 2, 256, 0, stream>>>(hb, Whb, pIU, pF, crow0, L);
        gate_kernel<<<(L + 1) >> 1, 256, 0, stream>>>(
            (const u32*)pre, (const u32*)pIU, (const u32*)pF, bI, bU, bF,
            (u32*)hb, (u32*)cb, out, s, crow0, L);
    }
}

// Round 11
// 198.842 us; speedup vs baseline: 1.2857x; 1.0724x over previous
//
#include <hip/hip_runtime.h>
#include <hip/hip_bf16.h>

// ChildSum TreeLSTM, complete 4-ary tree. N=65536, D=300(->320), H=256, K=4.
// Internal nodes [0,16384), leaves [16384,65536). Children of n: 4n+1..4n+4.
// Round 11: 2-phase double-buffered gll16 staging in all GEMMs (one barrier
// per K-step, staging of t+1 overlaps compute of t); hsumb[n] produced by
// gate (4-sibling groups) + hsum_big for all-leaf-children parents; merged
// conv kernel. c/h state bf16, gate math f32, fast exp2/rcp activations.

#define NTOT 65536
#define DD   300
#define KP   320
#define HH   256
#define LEAF_START 16384
#define LOG2E 1.4426950408889634f

typedef unsigned short u16;
typedef unsigned int   u32;
typedef __attribute__((ext_vector_type(8))) short bf16x8;
typedef __attribute__((ext_vector_type(4))) float f32x4;

// ---- ws layout (bytes) ----
#define OFF_HB    0ull                                   // [65537][256] bf16
#define OFF_CB    33554944ull                            // [65537][256] bf16
#define OFF_PRE   67109888ull                            // [16384][768] bf16
#define OFF_WXB   92275712ull                            // [768][320] bf16
#define OFF_WHB   92767232ull                            // [768][256] bf16
#define OFF_XB    93160448ull                            // [65536][320] bf16
#define OFF_PIU   135103488ull                           // [11008][512] bf16
#define OFF_PF    146375680ull                           // [43776][256] bf16
#define OFF_HSB   168788992ull                           // [16512][256] bf16 hsum by node id
#define OFF_BI    177243136ull                           // [256] f32
#define OFF_BU    177244160ull
#define OFF_BF    177245184ull

__device__ __forceinline__ float frcp(float x) { return __builtin_amdgcn_rcpf(x); }
__device__ __forceinline__ float fex2(float x) { return __builtin_amdgcn_exp2f(x); }
__device__ __forceinline__ float sigm(float x)  { return frcp(1.f + fex2(-LOG2E * x)); }
__device__ __forceinline__ float ftanh(float x) { return 1.f - 2.f * frcp(1.f + fex2(2.f * LOG2E * x)); }

__device__ __forceinline__ u16 f2bf(float f) {
    __hip_bfloat16 b = __float2bfloat16(f);
    u16 u; __builtin_memcpy(&u, &b, 2); return u;
}
__device__ __forceinline__ float bf2f(u16 b) {
    union { u32 u; float f; } v; v.u = ((u32)b) << 16;
    return v.f;
}
__device__ __forceinline__ int lidx(int r, int g) { return (r << 3) | (g ^ (r & 7)); }

__device__ __forceinline__ void gll16(const void* g, void* l) {
    __builtin_amdgcn_global_load_lds(
        (const __attribute__((address_space(1))) unsigned int*)g,
        (__attribute__((address_space(3))) unsigned int*)l, 16, 0, 0);
}

// ---- merged conversions: conv_x | conv_wx | conv_wh(+init) ----
__global__ __launch_bounds__(256) void conv_all(
    const float* __restrict__ X,
    const float* __restrict__ ixw, const float* __restrict__ uxw,
    const float* __restrict__ fiw,
    const float* __restrict__ ihw, const float* __restrict__ uhw,
    const float* __restrict__ fhw,
    const float* __restrict__ ixb, const float* __restrict__ ihb,
    const float* __restrict__ uxb, const float* __restrict__ uhb,
    const float* __restrict__ fib, const float* __restrict__ fhb,
    u32* __restrict__ Xb2, u32* __restrict__ Wxb2, u32* __restrict__ Whb2,
    u16* __restrict__ hb, u16* __restrict__ cb,
    float* __restrict__ bI, float* __restrict__ bU, float* __restrict__ bF)
{
    const int b = blockIdx.x;
    const int t = threadIdx.x;
    if (b < 2048) {                                      // X -> Xb
        const size_t total = (size_t)NTOT * 160;
        for (size_t id = (size_t)b * 256 + t; id < total; id += (size_t)2048 * 256) {
            const int node = (int)(id / 160);
            const int k    = ((int)(id % 160)) * 2;
            const float f0 = (k < DD)     ? X[(size_t)node * DD + k]     : 0.f;
            const float f1 = (k + 1 < DD) ? X[(size_t)node * DD + k + 1] : 0.f;
            Xb2[id] = (u32)f2bf(f0) | ((u32)f2bf(f1) << 16);
        }
    } else if (b < 2528) {                               // [ixw;uxw;fiw] -> Wxb
        const int b2 = b - 2048;
        const int total = 768 * 160;
        for (int id = b2 * 256 + t; id < total; id += 480 * 256) {
            const int row = id / 160;
            const int k   = (id % 160) * 2;
            const float* src = (row < 256) ? (ixw + (size_t)row * DD)
                             : (row < 512) ? (uxw + (size_t)(row - 256) * DD)
                                           : (fiw + (size_t)(row - 512) * DD);
            const float f0 = (k < DD)     ? src[k]     : 0.f;
            const float f1 = (k + 1 < DD) ? src[k + 1] : 0.f;
            Wxb2[id] = (u32)f2bf(f0) | ((u32)f2bf(f1) << 16);
        }
    } else {                                             // [ihw;uhw;fhw] -> Whb
        const int b3 = b - 2528;
        if (b3 == 0) {
            hb[(size_t)NTOT * HH + t] = 0;
            cb[(size_t)NTOT * HH + t] = 0;
            bI[t] = ixb[t] + ihb[t];
            bU[t] = uxb[t] + uhb[t];
            bF[t] = fib[t] + fhb[t];
        }
        const int total = 768 * 128;
        for (int id = b3 * 256 + t; id < total; id += 384 * 256) {
            const int row = id / 128;
            const int k   = (id % 128) * 2;
            const float* src = (row < 256) ? (ihw + (size_t)row * HH)
                             : (row < 512) ? (uhw + (size_t)(row - 256) * HH)
                                           : (fhw + (size_t)(row - 512) * HH);
            Whb2[id] = (u32)f2bf(src[k]) | ((u32)f2bf(src[k + 1]) << 16);
        }
    }
}

// ---- leaf GEMM (2-phase): 128 nodes x 64 ch; B = [64 ix | 64 ux] ----
__global__ __launch_bounds__(256) void leaf_gemm(
    const u16* __restrict__ Xb, const u16* __restrict__ Wxb,
    const float* __restrict__ bI, const float* __restrict__ bU,
    u16* __restrict__ hb, u16* __restrict__ cb)
{
    __shared__ bf16x8 Ash[2048];   // 2 x 1024 granules
    __shared__ bf16x8 Bsh[2048];

    const int tid  = threadIdx.x;
    const int lane = tid & 63;
    const int w    = tid >> 6;
    const int wr   = w >> 1, wc = w & 1;
    const int m16  = lane & 15, q = lane >> 4;

    const int row0   = LEAF_START + blockIdx.x * 128;
    const int chbase = blockIdx.y * 64;

    const bf16x8* __restrict__ Xv = (const bf16x8*)Xb;   // 40 granules/row
    const bf16x8* __restrict__ Wv = (const bf16x8*)Wxb;

    auto stage = [&](int kt, int buf) {
        const int base = buf << 10;
        #pragma unroll
        for (int i = 0; i < 4; ++i) {
            const int sI = w * 256 + i * 64 + lane;
            const int r = sI >> 3, gs = sI & 7;
            const int g = gs ^ (r & 7);
            gll16(Xv + (size_t)(row0 + r) * 40 + kt * 8 + g, &Ash[base + sI]);
        }
        #pragma unroll
        for (int i = 0; i < 4; ++i) {
            const int sI = w * 256 + i * 64 + lane;
            const int br = sI >> 3, gs = sI & 7;
            const int g = gs ^ (br & 7);
            const int srow = ((br >> 6) << 8) + chbase + (br & 63);
            gll16(Wv + (size_t)srow * 40 + kt * 8 + g, &Bsh[base + sI]);
        }
    };

    f32x4 accI[4][2], accU[4][2];
    #pragma unroll
    for (int mf = 0; mf < 4; ++mf)
        #pragma unroll
        for (int nf = 0; nf < 2; ++nf) { accI[mf][nf] = (f32x4)0.f; accU[mf][nf] = (f32x4)0.f; }

    stage(0, 0);
    __syncthreads();
    for (int kt = 0; kt < 5; ++kt) {
        const int cur = kt & 1;
        if (kt < 4) stage(kt + 1, cur ^ 1);
        const int base = cur << 10;
        #pragma unroll
        for (int ks = 0; ks < 2; ++ks) {
            const int kg = ks * 4 + q;
            bf16x8 a[4], bIv[2], bUv[2];
            #pragma unroll
            for (int mf = 0; mf < 4; ++mf)
                a[mf] = Ash[base + lidx(wr * 64 + mf * 16 + m16, kg)];
            #pragma unroll
            for (int nf = 0; nf < 2; ++nf) {
                bIv[nf] = Bsh[base + lidx(wc * 32 + nf * 16 + m16, kg)];
                bUv[nf] = Bsh[base + lidx(64 + wc * 32 + nf * 16 + m16, kg)];
            }
            #pragma unroll
            for (int mf = 0; mf < 4; ++mf)
                #pragma unroll
                for (int nf = 0; nf < 2; ++nf) {
                    accI[mf][nf] = __builtin_amdgcn_mfma_f32_16x16x32_bf16(
                        a[mf], bIv[nf], accI[mf][nf], 0, 0, 0);
                    accU[mf][nf] = __builtin_amdgcn_mfma_f32_16x16x32_bf16(
                        a[mf], bUv[nf], accU[mf][nf], 0, 0, 0);
                }
        }
        __syncthreads();
    }

    #pragma unroll
    for (int nf = 0; nf < 2; ++nf) {
        const int ch = chbase + wc * 32 + nf * 16 + m16;
        const float bi = bI[ch];               // recurrent biases apply at leaves
        const float bu = bU[ch];
        #pragma unroll
        for (int mf = 0; mf < 4; ++mf) {
            #pragma unroll
            for (int r4 = 0; r4 < 4; ++r4) {
                const float cn = sigm(accI[mf][nf][r4] + bi) * ftanh(accU[mf][nf][r4] + bu);
                const int node = row0 + wr * 64 + mf * 16 + q * 4 + r4;
                const size_t off = (size_t)node * HH + ch;
                cb[off] = f2bf(cn);
                hb[off] = f2bf(ftanh(cn));
            }
        }
    }
}

// ---- input-proj GEMM (2-phase): [16384 x 320] x [320 x 768] -> pre ----
__global__ __launch_bounds__(256) void proj_gemm(const u16* __restrict__ Xb,
                                                 const u16* __restrict__ Wxb,
                                                 u16* __restrict__ pre)
{
    __shared__ bf16x8 Ash[2048];
    __shared__ bf16x8 Bsh[2048];

    const int tid  = threadIdx.x;
    const int lane = tid & 63;
    const int w    = tid >> 6;
    const int wr   = w >> 1, wc = w & 1;
    const int m16  = lane & 15, q = lane >> 4;

    const int row0 = blockIdx.x * 128;
    const int n0   = blockIdx.y * 128;

    const bf16x8* __restrict__ Xv = (const bf16x8*)Xb;
    const bf16x8* __restrict__ Wv = (const bf16x8*)Wxb;

    auto stage = [&](int kt, int buf) {
        const int base = buf << 10;
        #pragma unroll
        for (int i = 0; i < 4; ++i) {
            const int sI = w * 256 + i * 64 + lane;
            const int r = sI >> 3, gs = sI & 7;
            const int g = gs ^ (r & 7);
            gll16(Xv + (size_t)(row0 + r) * 40 + kt * 8 + g, &Ash[base + sI]);
        }
        #pragma unroll
        for (int i = 0; i < 4; ++i) {
            const int sI = w * 256 + i * 64 + lane;
            const int br = sI >> 3, gs = sI & 7;
            const int g = gs ^ (br & 7);
            gll16(Wv + (size_t)(n0 + br) * 40 + kt * 8 + g, &Bsh[base + sI]);
        }
    };

    f32x4 acc[4][4];
    #pragma unroll
    for (int mf = 0; mf < 4; ++mf)
        #pragma unroll
        for (int nf = 0; nf < 4; ++nf) acc[mf][nf] = (f32x4)0.f;

    stage(0, 0);
    __syncthreads();
    for (int kt = 0; kt < 5; ++kt) {
        const int cur = kt & 1;
        if (kt < 4) stage(kt + 1, cur ^ 1);
        const int base = cur << 10;
        #pragma unroll
        for (int ks = 0; ks < 2; ++ks) {
            const int kg = ks * 4 + q;
            bf16x8 a[4], b[4];
            #pragma unroll
            for (int mf = 0; mf < 4; ++mf)
                a[mf] = Ash[base + lidx(wr * 64 + mf * 16 + m16, kg)];
            #pragma unroll
            for (int nf = 0; nf < 4; ++nf)
                b[nf] = Bsh[base + lidx(wc * 64 + nf * 16 + m16, kg)];
            #pragma unroll
            for (int mf = 0; mf < 4; ++mf)
                #pragma unroll
                for (int nf = 0; nf < 4; ++nf)
                    acc[mf][nf] = __builtin_amdgcn_mfma_f32_16x16x32_bf16(
                        a[mf], b[nf], acc[mf][nf], 0, 0, 0);
        }
        __syncthreads();
    }

    #pragma unroll
    for (int mf = 0; mf < 4; ++mf)
        #pragma unroll
        for (int nf = 0; nf < 4; ++nf) {
            const int col = n0 + wc * 64 + nf * 16 + m16;
            #pragma unroll
            for (int r4 = 0; r4 < 4; ++r4) {
                const int node = row0 + wr * 64 + mf * 16 + q * 4 + r4;
                pre[(size_t)node * 768 + col] = f2bf(acc[mf][nf][r4]);
            }
        }
}

// ---- hsumb for all-leaf-children parents p in [4096,16384) ----
__global__ __launch_bounds__(256) void hsum_big(const u32* __restrict__ hb2,
                                                u32* __restrict__ hsumb2)
{
    const int id = blockIdx.x * 256 + threadIdx.x;
    const int total = 12288 * 128;
    if (id >= total) return;
    const int ploc = id >> 7, j2 = id & 127;
    const int p = 4096 + ploc;
    const int c0 = 4 * p + 1;                  // >= 16385: all leaves (child 65536 = pad)
    float s0 = 0.f, s1 = 0.f;
    #pragma unroll
    for (int k = 0; k < 4; ++k) {
        const u32 v = hb2[(size_t)(c0 + k) * 128 + j2];
        s0 += bf2f((u16)v);
        s1 += bf2f((u16)(v >> 16));
    }
    hsumb2[(size_t)p * 128 + j2] = (u32)f2bf(s0) | ((u32)f2bf(s1) << 16);
}

// ---- per-level recurrent GEMM (2-phase, uniform gll16) ----
// IU: hsumb[s+row] x Whb[0:512]^T -> projIU ; F: hb[crow0+row] x Whb[512:768]^T -> projF
__global__ __launch_bounds__(256) void rec_gemm(const u16* __restrict__ hb,
                                                const u16* __restrict__ hsumb,
                                                const u16* __restrict__ Whb,
                                                u16* __restrict__ projIU,
                                                u16* __restrict__ projF,
                                                int crow0, int prow0, int L)
{
    __shared__ bf16x8 Ash[2048];
    __shared__ bf16x8 Bsh[2048];

    const int nIUrb = (L + 127) >> 7;
    const int bid   = blockIdx.x;

    bool isIU; int rb, cbk;
    if (bid < nIUrb * 4) { isIU = true;  rb = bid >> 2; cbk = bid & 3; }
    else { isIU = false; const int b2 = bid - nIUrb * 4; rb = b2 >> 1; cbk = b2 & 1; }

    const int row0  = rb * 128;
    const int Brow0 = isIU ? cbk * 128 : 512 + cbk * 128;
    const int ocol0 = cbk * 128;
    u16* __restrict__ out = isIU ? projIU : projF;
    const int ostride = isIU ? 512 : 256;

    const int tid  = threadIdx.x;
    const int lane = tid & 63;
    const int w    = tid >> 6;
    const int wr   = w >> 1, wc = w & 1;
    const int m16  = lane & 15, q = lane >> 4;

    const bf16x8* __restrict__ Av = isIU ? (const bf16x8*)hsumb : (const bf16x8*)hb;
    const bf16x8* __restrict__ Wv = (const bf16x8*)Whb;          // 32 granules/row

    auto stage = [&](int kt, int buf) {
        const int base = buf << 10;
        #pragma unroll
        for (int i = 0; i < 4; ++i) {
            const int sI = w * 256 + i * 64 + lane;
            const int r = sI >> 3, gs = sI & 7;
            const int g = gs ^ (r & 7);
            int arow;
            if (isIU) arow = prow0 + row0 + r;
            else { arow = crow0 + row0 + r; if (arow > NTOT) arow = NTOT; }
            gll16(Av + (size_t)arow * 32 + kt * 8 + g, &Ash[base + sI]);
        }
        #pragma unroll
        for (int i = 0; i < 4; ++i) {
            const int sI = w * 256 + i * 64 + lane;
            const int br = sI >> 3, gs = sI & 7;
            const int g = gs ^ (br & 7);
            gll16(Wv + (size_t)(Brow0 + br) * 32 + kt * 8 + g, &Bsh[base + sI]);
        }
    };

    f32x4 acc[4][4];
    #pragma unroll
    for (int mf = 0; mf < 4; ++mf)
        #pragma unroll
        for (int nf = 0; nf < 4; ++nf) acc[mf][nf] = (f32x4)0.f;

    stage(0, 0);
    __syncthreads();
    for (int kt = 0; kt < 4; ++kt) {
        const int cur = kt & 1;
        if (kt < 3) stage(kt + 1, cur ^ 1);
        const int base = cur << 10;
        #pragma unroll
        for (int ks = 0; ks < 2; ++ks) {
            const int kg = ks * 4 + q;
            bf16x8 a[4], b[4];
            #pragma unroll
            for (int mf = 0; mf < 4; ++mf)
                a[mf] = Ash[base + lidx(wr * 64 + mf * 16 + m16, kg)];
            #pragma unroll
            for (int nf = 0; nf < 4; ++nf)
                b[nf] = Bsh[base + lidx(wc * 64 + nf * 16 + m16, kg)];
            #pragma unroll
            for (int mf = 0; mf < 4; ++mf)
                #pragma unroll
                for (int nf = 0; nf < 4; ++nf)
                    acc[mf][nf] = __builtin_amdgcn_mfma_f32_16x16x32_bf16(
                        a[mf], b[nf], acc[mf][nf], 0, 0, 0);
        }
        __syncthreads();
    }

    #pragma unroll
    for (int mf = 0; mf < 4; ++mf)
        #pragma unroll
        for (int nf = 0; nf < 4; ++nf) {
            const int col = ocol0 + wc * 64 + nf * 16 + m16;
            #pragma unroll
            for (int r4 = 0; r4 < 4; ++r4) {
                const int orow = row0 + wr * 64 + mf * 16 + q * 4 + r4;
                out[(size_t)orow * ostride + col] = f2bf(acc[mf][nf][r4]);
            }
        }
}

// ---- per-level gates: thread owns a 4-sibling group (2 channels), writes
// h, c and hsumb[parent]; out-of-level siblings (leaf tail) read h from hb ----
__global__ __launch_bounds__(256) void gate_kernel(
    const u32* __restrict__ pre2, const u32* __restrict__ pIU2,
    const u32* __restrict__ pF2,
    const float* __restrict__ bI, const float* __restrict__ bU,
    const float* __restrict__ bF,
    u32* __restrict__ hb2, u32* __restrict__ cb2, u32* __restrict__ hsumb2,
    float* __restrict__ out, int s, int crow0, int L)
{
    const int t  = threadIdx.x;
    const int j2 = t & 127;
    const float2 vbi = ((const float2*)bI)[j2];
    const float2 vbu = ((const float2*)bU)[j2];
    const float2 vbf = ((const float2*)bF)[j2];

    if (L == 1) {                                        // root node 0
        if (t >= 128) return;
        const u32 pi = pre2[j2];
        const u32 pu = pre2[128 + j2];
        const u32 pf = pre2[256 + j2];
        const u32 ri = pIU2[j2];
        const u32 ru = pIU2[128 + j2];
        const float aI0 = bf2f((u16)pi) + bf2f((u16)ri) + vbi.x;
        const float aI1 = bf2f((u16)(pi >> 16)) + bf2f((u16)(ri >> 16)) + vbi.y;
        const float aU0 = bf2f((u16)pu) + bf2f((u16)ru) + vbu.x;
        const float aU1 = bf2f((u16)(pu >> 16)) + bf2f((u16)(ru >> 16)) + vbu.y;
        const float fp0 = bf2f((u16)pf) + vbf.x;
        const float fp1 = bf2f((u16)(pf >> 16)) + vbf.y;
        float fc0 = 0.f, fc1 = 0.f;
        #pragma unroll
        for (int kk = 0; kk < 4; ++kk) {
            const u32 rf = pF2[(size_t)kk * 128 + j2];
            const u32 cc = cb2[(size_t)(crow0 + kk) * 128 + j2];
            fc0 = fmaf(sigm(fp0 + bf2f((u16)rf)), bf2f((u16)cc), fc0);
            fc1 = fmaf(sigm(fp1 + bf2f((u16)(rf >> 16))), bf2f((u16)(cc >> 16)), fc1);
        }
        const float cn0 = fmaf(sigm(aI0), ftanh(aU0), fc0);
        const float cn1 = fmaf(sigm(aI1), ftanh(aU1), fc1);
        const float hn0 = ftanh(cn0);
        const float hn1 = ftanh(cn1);
        hb2[j2] = (u32)f2bf(hn0) | ((u32)f2bf(hn1) << 16);
        cb2[j2] = (u32)f2bf(cn0) | ((u32)f2bf(cn1) << 16);
        ((float2*)out)[j2] = make_float2(hn0, hn1);
        ((float2*)(out + 256))[j2] = make_float2(cn0, cn1);
        return;
    }

    const int ng = (L + 3) >> 2;
    const int g  = blockIdx.x * 2 + (t >> 7);
    if (g >= ng) return;
    const int p = ((s - 1) >> 2) + g;                    // parent node (global)

    float hs0 = 0.f, hs1 = 0.f;
    #pragma unroll
    for (int k = 0; k < 4; ++k) {
        const int nloc = 4 * g + k;
        const int n = s + nloc;
        if (nloc < L) {
            const u32 pi = pre2[(size_t)n * 384 + j2];
            const u32 pu = pre2[(size_t)n * 384 + 128 + j2];
            const u32 pf = pre2[(size_t)n * 384 + 256 + j2];
            const u32 ri = pIU2[(size_t)nloc * 256 + j2];
            const u32 ru = pIU2[(size_t)nloc * 256 + 128 + j2];
            const float aI0 = bf2f((u16)pi) + bf2f((u16)ri) + vbi.x;
            const float aI1 = bf2f((u16)(pi >> 16)) + bf2f((u16)(ri >> 16)) + vbi.y;
            const float aU0 = bf2f((u16)pu) + bf2f((u16)ru) + vbu.x;
            const float aU1 = bf2f((u16)(pu >> 16)) + bf2f((u16)(ru >> 16)) + vbu.y;
            const float fp0 = bf2f((u16)pf) + vbf.x;
            const float fp1 = bf2f((u16)(pf >> 16)) + vbf.y;
            float fc0 = 0.f, fc1 = 0.f;
            #pragma unroll
            for (int kk = 0; kk < 4; ++kk) {
                const u32 rf = pF2[(size_t)(4 * nloc + kk) * 128 + j2];
                const u32 cc = cb2[(size_t)(crow0 + 4 * nloc + kk) * 128 + j2];
                fc0 = fmaf(sigm(fp0 + bf2f((u16)rf)), bf2f((u16)cc), fc0);
                fc1 = fmaf(sigm(fp1 + bf2f((u16)(rf >> 16))), bf2f((u16)(cc >> 16)), fc1);
            }
            const float cn0 = fmaf(sigm(aI0), ftanh(aU0), fc0);
            const float cn1 = fmaf(sigm(aI1), ftanh(aU1), fc1);
            const float hn0 = ftanh(cn0);
            const float hn1 = ftanh(cn1);
            hb2[(size_t)n * 128 + j2] = (u32)f2bf(hn0) | ((u32)f2bf(hn1) << 16);
            cb2[(size_t)n * 128 + j2] = (u32)f2bf(cn0) | ((u32)f2bf(cn1) << 16);
            hs0 += hn0; hs1 += hn1;
        } else {
            // sibling beyond level end is a leaf (big level only): h already in hb
            const u32 v = hb2[(size_t)n * 128 + j2];
            hs0 += bf2f((u16)v);
            hs1 += bf2f((u16)(v >> 16));
        }
    }
    hsumb2[(size_t)p * 128 + j2] = (u32)f2bf(hs0) | ((u32)f2bf(hs1) << 16);
}

extern "C" void kernel_launch(void* const* d_in, const int* in_sizes, int n_in,
                              void* d_out, int out_size, void* d_ws, size_t ws_size,
                              hipStream_t stream) {
    const float* X   = (const float*)d_in[0];
    const float* ixw = (const float*)d_in[1];
    const float* ixb = (const float*)d_in[2];
    const float* ihw = (const float*)d_in[3];
    const float* ihb = (const float*)d_in[4];
    const float* uxw = (const float*)d_in[5];
    const float* uxb = (const float*)d_in[6];
    const float* uhw = (const float*)d_in[7];
    const float* uhb = (const float*)d_in[8];
    const float* fiw = (const float*)d_in[9];
    const float* fib = (const float*)d_in[10];
    const float* fhw = (const float*)d_in[11];
    const float* fhb = (const float*)d_in[12];
    float* out = (float*)d_out;

    char* ws = (char*)d_ws;
    u16* hb   = (u16*)(ws + OFF_HB);
    u16* cb   = (u16*)(ws + OFF_CB);
    u16* pre  = (u16*)(ws + OFF_PRE);
    u16* Wxb  = (u16*)(ws + OFF_WXB);
    u16* Whb  = (u16*)(ws + OFF_WHB);
    u16* Xb   = (u16*)(ws + OFF_XB);
    u16* pIU  = (u16*)(ws + OFF_PIU);
    u16* pF   = (u16*)(ws + OFF_PF);
    u16* hsb  = (u16*)(ws + OFF_HSB);
    float* bI = (float*)(ws + OFF_BI);
    float* bU = (float*)(ws + OFF_BU);
    float* bF = (float*)(ws + OFF_BF);

    conv_all<<<2912, 256, 0, stream>>>(X, ixw, uxw, fiw, ihw, uhw, fhw,
        ixb, ihb, uxb, uhb, fib, fhb,
        (u32*)Xb, (u32*)Wxb, (u32*)Whb, hb, cb, bI, bU, bF);

    leaf_gemm<<<dim3(384, 4), 256, 0, stream>>>(Xb, Wxb, bI, bU, hb, cb);
    proj_gemm<<<dim3(128, 6), 256, 0, stream>>>(Xb, Wxb, pre);
    hsum_big<<<6144, 256, 0, stream>>>((const u32*)hb, (u32*)hsb);

    const int starts[8] = {5461, 1365, 341, 85, 21, 5, 1, 0};
    const int ends[8]   = {16384, 5461, 1365, 341, 85, 21, 5, 1};
    for (int l = 0; l < 8; ++l) {
        const int s = starts[l], e = ends[l];
        const int L = e - s;
        const int crow0 = 4 * s + 1;
        const int nIUrb = (L + 127) >> 7;
        const int nFrb  = (4 * L + 127) >> 7;
        rec_gemm<<<nIUrb * 4 + nFrb * 2, 256, 0, stream>>>(hb, hsb, Whb, pIU, pF,
                                                           crow0, s, L);
        const int ng = (L + 3) >> 2;
        gate_kernel<<<(ng + 1) >> 1, 256, 0, stream>>>(
            (const u32*)pre, (const u32*)pIU, (const u32*)pF, bI, bU, bF,
            (u32*)hb, (u32*)cb, (u32*)hsb, out, s, crow0, L);
    }
}

// Round 12
// 198.251 us; speedup vs baseline: 1.2895x; 1.0030x over previous
//
#include <hip/hip_runtime.h>
#include <hip/hip_bf16.h>

// ChildSum TreeLSTM, complete 4-ary tree. N=65536, D=300(->320), H=256, K=4.
// Internal [0,16384), leaves [16384,65536). Children of n: 4n+1..4n+4.
// Round 12: forget-gate fused into rec F epilogue (fc f32 buffer replaces
// projF + child-c reads); level-0 IU hsum reg-staged from leaves; hsum_small
// (parents 4096..5460) fused into gate0 launch; leaf+proj merged. 18 launches.

#define NTOT 65536
#define DD   300
#define KP   320
#define HH   256
#define LEAF_START 16384
#define LOG2E 1.4426950408889634f

typedef unsigned short u16;
typedef unsigned int   u32;
typedef __attribute__((ext_vector_type(8))) short bf16x8;
typedef __attribute__((ext_vector_type(4))) float f32x4;

union BF8 { bf16x8 v; u16 u[8]; };

// ---- ws layout (bytes) ----
#define OFF_HB    0ull                                   // [65537][256] bf16
#define OFF_CB    33554944ull                            // [65537][256] bf16
#define OFF_PRE   67109888ull                            // [16384][768] bf16
#define OFF_WXB   92275712ull                            // [768][320] bf16
#define OFF_WHB   92767232ull                            // [768][256] bf16
#define OFF_XB    93160448ull                            // [65536][320] bf16
#define OFF_PIU   135103488ull                           // [11008][512] bf16
#define OFF_FC    146375680ull                           // [11008][256] f32
#define OFF_HSB   157647872ull                           // [16512][256] bf16 (node-indexed hsum)
#define OFF_BI    166102016ull                           // [256] f32
#define OFF_BU    166103040ull
#define OFF_BF    166104064ull

__device__ __forceinline__ float frcp(float x) { return __builtin_amdgcn_rcpf(x); }
__device__ __forceinline__ float fex2(float x) { return __builtin_amdgcn_exp2f(x); }
__device__ __forceinline__ float sigm(float x)  { return frcp(1.f + fex2(-LOG2E * x)); }
__device__ __forceinline__ float ftanh(float x) { return 1.f - 2.f * frcp(1.f + fex2(2.f * LOG2E * x)); }

__device__ __forceinline__ u16 f2bf(float f) {
    __hip_bfloat16 b = __float2bfloat16(f);
    u16 u; __builtin_memcpy(&u, &b, 2); return u;
}
__device__ __forceinline__ float bf2f(u16 b) {
    union { u32 u; float f; } v; v.u = ((u32)b) << 16;
    return v.f;
}
__device__ __forceinline__ int lidx(int r, int g) { return (r << 3) | (g ^ (r & 7)); }

__device__ __forceinline__ void gll16(const void* g, void* l) {
    __builtin_amdgcn_global_load_lds(
        (const __attribute__((address_space(1))) unsigned int*)g,
        (__attribute__((address_space(3))) unsigned int*)l, 16, 0, 0);
}

// ---- merged conversions: conv_x | conv_wx | conv_wh(+init) ----
__global__ __launch_bounds__(256) void conv_all(
    const float* __restrict__ X,
    const float* __restrict__ ixw, const float* __restrict__ uxw,
    const float* __restrict__ fiw,
    const float* __restrict__ ihw, const float* __restrict__ uhw,
    const float* __restrict__ fhw,
    const float* __restrict__ ixb, const float* __restrict__ ihb,
    const float* __restrict__ uxb, const float* __restrict__ uhb,
    const float* __restrict__ fib, const float* __restrict__ fhb,
    u32* __restrict__ Xb2, u32* __restrict__ Wxb2, u32* __restrict__ Whb2,
    u16* __restrict__ hb, u16* __restrict__ cb,
    float* __restrict__ bI, float* __restrict__ bU, float* __restrict__ bF)
{
    const int b = blockIdx.x;
    const int t = threadIdx.x;
    if (b < 2048) {                                      // X -> Xb
        const size_t total = (size_t)NTOT * 160;
        for (size_t id = (size_t)b * 256 + t; id < total; id += (size_t)2048 * 256) {
            const int node = (int)(id / 160);
            const int k    = ((int)(id % 160)) * 2;
            const float f0 = (k < DD)     ? X[(size_t)node * DD + k]     : 0.f;
            const float f1 = (k + 1 < DD) ? X[(size_t)node * DD + k + 1] : 0.f;
            Xb2[id] = (u32)f2bf(f0) | ((u32)f2bf(f1) << 16);
        }
    } else if (b < 2528) {                               // [ixw;uxw;fiw] -> Wxb
        const int b2 = b - 2048;
        const int total = 768 * 160;
        for (int id = b2 * 256 + t; id < total; id += 480 * 256) {
            const int row = id / 160;
            const int k   = (id % 160) * 2;
            const float* src = (row < 256) ? (ixw + (size_t)row * DD)
                             : (row < 512) ? (uxw + (size_t)(row - 256) * DD)
                                           : (fiw + (size_t)(row - 512) * DD);
            const float f0 = (k < DD)     ? src[k]     : 0.f;
            const float f1 = (k + 1 < DD) ? src[k + 1] : 0.f;
            Wxb2[id] = (u32)f2bf(f0) | ((u32)f2bf(f1) << 16);
        }
    } else {                                             // [ihw;uhw;fhw] -> Whb
        const int b3 = b - 2528;
        if (b3 == 0) {
            hb[(size_t)NTOT * HH + t] = 0;
            cb[(size_t)NTOT * HH + t] = 0;
            bI[t] = ixb[t] + ihb[t];
            bU[t] = uxb[t] + uhb[t];
            bF[t] = fib[t] + fhb[t];
        }
        const int total = 768 * 128;
        for (int id = b3 * 256 + t; id < total; id += 384 * 256) {
            const int row = id / 128;
            const int k   = (id % 128) * 2;
            const float* src = (row < 256) ? (ihw + (size_t)row * HH)
                             : (row < 512) ? (uhw + (size_t)(row - 256) * HH)
                                           : (fhw + (size_t)(row - 512) * HH);
            Whb2[id] = (u32)f2bf(src[k]) | ((u32)f2bf(src[k + 1]) << 16);
        }
    }
}

// ---- merged leaf (b<1536) + proj (b>=1536) GEMM, 2-phase gll16 staging ----
__global__ __launch_bounds__(256) void lp_gemm(
    const u16* __restrict__ Xb, const u16* __restrict__ Wxb,
    const float* __restrict__ bI, const float* __restrict__ bU,
    u16* __restrict__ hb, u16* __restrict__ cb, u16* __restrict__ pre)
{
    __shared__ bf16x8 Ash[2048];
    __shared__ bf16x8 Bsh[2048];

    const int tid  = threadIdx.x;
    const int lane = tid & 63;
    const int w    = tid >> 6;
    const int wr   = w >> 1, wc = w & 1;
    const int m16  = lane & 15, q = lane >> 4;

    const bf16x8* __restrict__ Xv = (const bf16x8*)Xb;   // 40 granules/row
    const bf16x8* __restrict__ Wv = (const bf16x8*)Wxb;

    if (blockIdx.x < 1536) {
        // ================= leaf path: 128 nodes x 64 ch, B = [64ix|64ux] =====
        const int row0   = LEAF_START + (blockIdx.x >> 2) * 128;
        const int chbase = (blockIdx.x & 3) * 64;

        auto stage = [&](int kt, int buf) {
            const int base = buf << 10;
            #pragma unroll
            for (int i = 0; i < 4; ++i) {
                const int sI = w * 256 + i * 64 + lane;
                const int r = sI >> 3, gs = sI & 7;
                const int g = gs ^ (r & 7);
                gll16(Xv + (size_t)(row0 + r) * 40 + kt * 8 + g, &Ash[base + sI]);
            }
            #pragma unroll
            for (int i = 0; i < 4; ++i) {
                const int sI = w * 256 + i * 64 + lane;
                const int br = sI >> 3, gs = sI & 7;
                const int g = gs ^ (br & 7);
                const int srow = ((br >> 6) << 8) + chbase + (br & 63);
                gll16(Wv + (size_t)srow * 40 + kt * 8 + g, &Bsh[base + sI]);
            }
        };

        f32x4 accI[4][2], accU[4][2];
        #pragma unroll
        for (int mf = 0; mf < 4; ++mf)
            #pragma unroll
            for (int nf = 0; nf < 2; ++nf) { accI[mf][nf] = (f32x4)0.f; accU[mf][nf] = (f32x4)0.f; }

        stage(0, 0);
        __syncthreads();
        for (int kt = 0; kt < 5; ++kt) {
            const int cur = kt & 1;
            if (kt < 4) stage(kt + 1, cur ^ 1);
            const int base = cur << 10;
            #pragma unroll
            for (int ks = 0; ks < 2; ++ks) {
                const int kg = ks * 4 + q;
                bf16x8 a[4], bIv[2], bUv[2];
                #pragma unroll
                for (int mf = 0; mf < 4; ++mf)
                    a[mf] = Ash[base + lidx(wr * 64 + mf * 16 + m16, kg)];
                #pragma unroll
                for (int nf = 0; nf < 2; ++nf) {
                    bIv[nf] = Bsh[base + lidx(wc * 32 + nf * 16 + m16, kg)];
                    bUv[nf] = Bsh[base + lidx(64 + wc * 32 + nf * 16 + m16, kg)];
                }
                #pragma unroll
                for (int mf = 0; mf < 4; ++mf)
                    #pragma unroll
                    for (int nf = 0; nf < 2; ++nf) {
                        accI[mf][nf] = __builtin_amdgcn_mfma_f32_16x16x32_bf16(
                            a[mf], bIv[nf], accI[mf][nf], 0, 0, 0);
                        accU[mf][nf] = __builtin_amdgcn_mfma_f32_16x16x32_bf16(
                            a[mf], bUv[nf], accU[mf][nf], 0, 0, 0);
                    }
            }
            __syncthreads();
        }

        #pragma unroll
        for (int nf = 0; nf < 2; ++nf) {
            const int ch = chbase + wc * 32 + nf * 16 + m16;
            const float bi = bI[ch];           // recurrent biases apply at leaves
            const float bu = bU[ch];
            #pragma unroll
            for (int mf = 0; mf < 4; ++mf) {
                #pragma unroll
                for (int r4 = 0; r4 < 4; ++r4) {
                    const float cn = sigm(accI[mf][nf][r4] + bi) * ftanh(accU[mf][nf][r4] + bu);
                    const int node = row0 + wr * 64 + mf * 16 + q * 4 + r4;
                    const size_t off = (size_t)node * HH + ch;
                    cb[off] = f2bf(cn);
                    hb[off] = f2bf(ftanh(cn));
                }
            }
        }
    } else {
        // ================= proj path: [16384 x 320] x [320 x 768] -> pre =====
        const int pb   = blockIdx.x - 1536;
        const int row0 = (pb / 6) * 128;
        const int n0   = (pb % 6) * 128;

        auto stage = [&](int kt, int buf) {
            const int base = buf << 10;
            #pragma unroll
            for (int i = 0; i < 4; ++i) {
                const int sI = w * 256 + i * 64 + lane;
                const int r = sI >> 3, gs = sI & 7;
                const int g = gs ^ (r & 7);
                gll16(Xv + (size_t)(row0 + r) * 40 + kt * 8 + g, &Ash[base + sI]);
            }
            #pragma unroll
            for (int i = 0; i < 4; ++i) {
                const int sI = w * 256 + i * 64 + lane;
                const int br = sI >> 3, gs = sI & 7;
                const int g = gs ^ (br & 7);
                gll16(Wv + (size_t)(n0 + br) * 40 + kt * 8 + g, &Bsh[base + sI]);
            }
        };

        f32x4 acc[4][4];
        #pragma unroll
        for (int mf = 0; mf < 4; ++mf)
            #pragma unroll
            for (int nf = 0; nf < 4; ++nf) acc[mf][nf] = (f32x4)0.f;

        stage(0, 0);
        __syncthreads();
        for (int kt = 0; kt < 5; ++kt) {
            const int cur = kt & 1;
            if (kt < 4) stage(kt + 1, cur ^ 1);
            const int base = cur << 10;
            #pragma unroll
            for (int ks = 0; ks < 2; ++ks) {
                const int kg = ks * 4 + q;
                bf16x8 a[4], b[4];
                #pragma unroll
                for (int mf = 0; mf < 4; ++mf)
                    a[mf] = Ash[base + lidx(wr * 64 + mf * 16 + m16, kg)];
                #pragma unroll
                for (int nf = 0; nf < 4; ++nf)
                    b[nf] = Bsh[base + lidx(wc * 64 + nf * 16 + m16, kg)];
                #pragma unroll
                for (int mf = 0; mf < 4; ++mf)
                    #pragma unroll
                    for (int nf = 0; nf < 4; ++nf)
                        acc[mf][nf] = __builtin_amdgcn_mfma_f32_16x16x32_bf16(
                            a[mf], b[nf], acc[mf][nf], 0, 0, 0);
            }
            __syncthreads();
        }

        #pragma unroll
        for (int mf = 0; mf < 4; ++mf)
            #pragma unroll
            for (int nf = 0; nf < 4; ++nf) {
                const int col = n0 + wc * 64 + nf * 16 + m16;
                #pragma unroll
                for (int r4 = 0; r4 < 4; ++r4) {
                    const int node = row0 + wr * 64 + mf * 16 + q * 4 + r4;
                    pre[(size_t)node * 768 + col] = f2bf(acc[mf][nf][r4]);
                }
            }
    }
}

// ---- per-level recurrent GEMM; F epilogue computes fc; level-0 IU reg-hsum ----
__global__ __launch_bounds__(256) void rec_gemm(
    const u16* __restrict__ hb, const u16* __restrict__ hsb,
    const u16* __restrict__ Whb, const u16* __restrict__ pre,
    const float* __restrict__ bF, const u16* __restrict__ cb,
    u16* __restrict__ projIU, float* __restrict__ fcbuf,
    int s, int crow0, int L, int bigIU)
{
    __shared__ bf16x8 Ash[2048];
    __shared__ bf16x8 Bsh[2048];

    const int nIUrb = (L + 127) >> 7;
    const int bid   = blockIdx.x;

    bool isIU; int rb, cbk;
    if (bid < nIUrb * 4) { isIU = true;  rb = bid >> 2; cbk = bid & 3; }
    else { isIU = false; const int b2 = bid - nIUrb * 4; rb = b2 >> 1; cbk = b2 & 1; }

    const int row0  = rb * 128;
    const int Brow0 = isIU ? cbk * 128 : 512 + cbk * 128;
    const int ocol0 = cbk * 128;

    const int tid  = threadIdx.x;
    const int lane = tid & 63;
    const int w    = tid >> 6;
    const int wr   = w >> 1, wc = w & 1;
    const int m16  = lane & 15, q = lane >> 4;

    const bf16x8* __restrict__ Hv = (const bf16x8*)hb;   // 32 granules/row
    const bf16x8* __restrict__ Sv = (const bf16x8*)hsb;
    const bf16x8* __restrict__ Wv = (const bf16x8*)Whb;

    auto stage = [&](int kt, int buf) {
        const int base = buf << 10;
        if (isIU && bigIU) {
            // reg-staged hsum of 4 contiguous leaf children
            #pragma unroll
            for (int i = 0; i < 4; ++i) {
                const int G = tid + i * 256;
                const int r = G >> 3, g = G & 7;
                bf16x8 val;
                if (row0 + r < L) {
                    const size_t cg0 = (size_t)(crow0 + 4 * (row0 + r)) * 32 + kt * 8 + g;
                    BF8 x0, x1, x2, x3, o;
                    x0.v = Hv[cg0]; x1.v = Hv[cg0 + 32];
                    x2.v = Hv[cg0 + 64]; x3.v = Hv[cg0 + 96];
                    #pragma unroll
                    for (int j = 0; j < 8; ++j)
                        o.u[j] = f2bf(bf2f(x0.u[j]) + bf2f(x1.u[j])
                                    + bf2f(x2.u[j]) + bf2f(x3.u[j]));
                    val = o.v;
                } else {
                    BF8 z;
                    #pragma unroll
                    for (int j = 0; j < 8; ++j) z.u[j] = 0;
                    val = z.v;
                }
                Ash[base + lidx(r, g)] = val;
            }
        } else {
            #pragma unroll
            for (int i = 0; i < 4; ++i) {
                const int sI = w * 256 + i * 64 + lane;
                const int r = sI >> 3, gs = sI & 7;
                const int g = gs ^ (r & 7);
                if (isIU) {
                    gll16(Sv + (size_t)(s + row0 + r) * 32 + kt * 8 + g, &Ash[base + sI]);
                } else {
                    int arow = crow0 + row0 + r;
                    if (arow > NTOT) arow = NTOT;        // zeroed pad row
                    gll16(Hv + (size_t)arow * 32 + kt * 8 + g, &Ash[base + sI]);
                }
            }
        }
        #pragma unroll
        for (int i = 0; i < 4; ++i) {
            const int sI = w * 256 + i * 64 + lane;
            const int br = sI >> 3, gs = sI & 7;
            const int g = gs ^ (br & 7);
            gll16(Wv + (size_t)(Brow0 + br) * 32 + kt * 8 + g, &Bsh[base + sI]);
        }
    };

    f32x4 acc[4][4];
    #pragma unroll
    for (int mf = 0; mf < 4; ++mf)
        #pragma unroll
        for (int nf = 0; nf < 4; ++nf) acc[mf][nf] = (f32x4)0.f;

    stage(0, 0);
    __syncthreads();
    for (int kt = 0; kt < 4; ++kt) {
        const int cur = kt & 1;
        if (kt < 3) stage(kt + 1, cur ^ 1);
        const int base = cur << 10;
        #pragma unroll
        for (int ks = 0; ks < 2; ++ks) {
            const int kg = ks * 4 + q;
            bf16x8 a[4], b[4];
            #pragma unroll
            for (int mf = 0; mf < 4; ++mf)
                a[mf] = Ash[base + lidx(wr * 64 + mf * 16 + m16, kg)];
            #pragma unroll
            for (int nf = 0; nf < 4; ++nf)
                b[nf] = Bsh[base + lidx(wc * 64 + nf * 16 + m16, kg)];
            #pragma unroll
            for (int mf = 0; mf < 4; ++mf)
                #pragma unroll
                for (int nf = 0; nf < 4; ++nf)
                    acc[mf][nf] = __builtin_amdgcn_mfma_f32_16x16x32_bf16(
                        a[mf], b[nf], acc[mf][nf], 0, 0, 0);
        }
        __syncthreads();
    }

    if (isIU) {
        #pragma unroll
        for (int mf = 0; mf < 4; ++mf)
            #pragma unroll
            for (int nf = 0; nf < 4; ++nf) {
                const int col = ocol0 + wc * 64 + nf * 16 + m16;
                #pragma unroll
                for (int r4 = 0; r4 < 4; ++r4) {
                    const int orow = row0 + wr * 64 + mf * 16 + q * 4 + r4;
                    projIU[(size_t)orow * 512 + col] = f2bf(acc[mf][nf][r4]);
                }
            }
    } else {
        // fc[parent, col] = sum over the 4 siblings (r4) of sigm(aFH+fpre)*c_child
        #pragma unroll
        for (int mf = 0; mf < 4; ++mf) {
            const int off  = wr * 64 + mf * 16 + q * 4;      // multiple of 4
            const int goff = (row0 + off) >> 2;              // parent local idx
            if (goff < L) {
                #pragma unroll
                for (int nf = 0; nf < 4; ++nf) {
                    const int col = ocol0 + wc * 64 + nf * 16 + m16;
                    const float fpre = bf2f(pre[(size_t)(s + goff) * 768 + 512 + col]) + bF[col];
                    float fc = 0.f;
                    #pragma unroll
                    for (int r4 = 0; r4 < 4; ++r4) {
                        int child = crow0 + row0 + off + r4;
                        if (child > NTOT) child = NTOT;      // pad (c=0)
                        const float cc = bf2f(cb[(size_t)child * HH + col]);
                        fc = fmaf(sigm(acc[mf][nf][r4] + fpre), cc, fc);
                    }
                    fcbuf[(size_t)goff * HH + col] = fc;
                }
            }
        }
    }
}

// ---- per-level gates (+ hsum_small partition on level 0) ----
__global__ __launch_bounds__(256) void gate_kernel(
    const u32* __restrict__ pre2, const u32* __restrict__ pIU2,
    const float* __restrict__ fcbuf,
    const float* __restrict__ bI, const float* __restrict__ bU,
    u32* __restrict__ hb2, u32* __restrict__ cb2, u32* __restrict__ hsumb2,
    float* __restrict__ out, int s, int L)
{
    const int t  = threadIdx.x;
    const int j2 = t & 127;

    if (L == 1) {                                        // root node 0
        if (t >= 128) return;
        const float2 vbi = ((const float2*)bI)[j2];
        const float2 vbu = ((const float2*)bU)[j2];
        const u32 pi = pre2[j2];
        const u32 pu = pre2[128 + j2];
        const u32 ri = pIU2[j2];
        const u32 ru = pIU2[128 + j2];
        const float aI0 = bf2f((u16)pi) + bf2f((u16)ri) + vbi.x;
        const float aI1 = bf2f((u16)(pi >> 16)) + bf2f((u16)(ri >> 16)) + vbi.y;
        const float aU0 = bf2f((u16)pu) + bf2f((u16)ru) + vbu.x;
        const float aU1 = bf2f((u16)(pu >> 16)) + bf2f((u16)(ru >> 16)) + vbu.y;
        const float2 fc = ((const float2*)fcbuf)[j2];
        const float cn0 = fmaf(sigm(aI0), ftanh(aU0), fc.x);
        const float cn1 = fmaf(sigm(aI1), ftanh(aU1), fc.y);
        const float hn0 = ftanh(cn0);
        const float hn1 = ftanh(cn1);
        hb2[j2] = (u32)f2bf(hn0) | ((u32)f2bf(hn1) << 16);
        cb2[j2] = (u32)f2bf(cn0) | ((u32)f2bf(cn1) << 16);
        ((float2*)out)[j2] = make_float2(hn0, hn1);
        ((float2*)(out + 256))[j2] = make_float2(cn0, cn1);
        return;
    }

    const int ng = (L + 3) >> 2;
    const int gateBlocks = (ng + 1) >> 1;
    if ((int)blockIdx.x >= gateBlocks) {
        // hsum_small: parents 4096..5460 (all-leaf children) — level-0 launch only
        const int id = ((int)blockIdx.x - gateBlocks) * 256 + t;
        if (id < 1365 * 128) {
            const int ploc = id >> 7, jj = id & 127;
            const int p = 4096 + ploc;
            const int c0 = 4 * p + 1;
            float s0 = 0.f, s1 = 0.f;
            #pragma unroll
            for (int k = 0; k < 4; ++k) {
                const u32 v = hb2[(size_t)(c0 + k) * 128 + jj];
                s0 += bf2f((u16)v);
                s1 += bf2f((u16)(v >> 16));
            }
            hsumb2[(size_t)p * 128 + jj] = (u32)f2bf(s0) | ((u32)f2bf(s1) << 16);
        }
        return;
    }

    const float2 vbi = ((const float2*)bI)[j2];
    const float2 vbu = ((const float2*)bU)[j2];
    const int g = blockIdx.x * 2 + (t >> 7);
    if (g >= ng) return;
    const int p = ((s - 1) >> 2) + g;                    // parent node (global)

    float hs0 = 0.f, hs1 = 0.f;
    #pragma unroll
    for (int k = 0; k < 4; ++k) {
        const int nloc = 4 * g + k;
        const int n = s + nloc;
        if (nloc < L) {
            const u32 pi = pre2[(size_t)n * 384 + j2];
            const u32 pu = pre2[(size_t)n * 384 + 128 + j2];
            const u32 ri = pIU2[(size_t)nloc * 256 + j2];
            const u32 ru = pIU2[(size_t)nloc * 256 + 128 + j2];
            const float aI0 = bf2f((u16)pi) + bf2f((u16)ri) + vbi.x;
            const float aI1 = bf2f((u16)(pi >> 16)) + bf2f((u16)(ri >> 16)) + vbi.y;
            const float aU0 = bf2f((u16)pu) + bf2f((u16)ru) + vbu.x;
            const float aU1 = bf2f((u16)(pu >> 16)) + bf2f((u16)(ru >> 16)) + vbu.y;
            const float2 fc = ((const float2*)fcbuf)[(size_t)nloc * 128 + j2];
            const float cn0 = fmaf(sigm(aI0), ftanh(aU0), fc.x);
            const float cn1 = fmaf(sigm(aI1), ftanh(aU1), fc.y);
            const float hn0 = ftanh(cn0);
            const float hn1 = ftanh(cn1);
            hb2[(size_t)n * 128 + j2] = (u32)f2bf(hn0) | ((u32)f2bf(hn1) << 16);
            cb2[(size_t)n * 128 + j2] = (u32)f2bf(cn0) | ((u32)f2bf(cn1) << 16);
            hs0 += hn0; hs1 += hn1;
        } else {
            const u32 v = hb2[(size_t)n * 128 + j2];     // leaf sibling (mixed group)
            hs0 += bf2f((u16)v);
            hs1 += bf2f((u16)(v >> 16));
        }
    }
    hsumb2[(size_t)p * 128 + j2] = (u32)f2bf(hs0) | ((u32)f2bf(hs1) << 16);
}

extern "C" void kernel_launch(void* const* d_in, const int* in_sizes, int n_in,
                              void* d_out, int out_size, void* d_ws, size_t ws_size,
                              hipStream_t stream) {
    const float* X   = (const float*)d_in[0];
    const float* ixw = (const float*)d_in[1];
    const float* ixb = (const float*)d_in[2];
    const float* ihw = (const float*)d_in[3];
    const float* ihb = (const float*)d_in[4];
    const float* uxw = (const float*)d_in[5];
    const float* uxb = (const float*)d_in[6];
    const float* uhw = (const float*)d_in[7];
    const float* uhb = (const float*)d_in[8];
    const float* fiw = (const float*)d_in[9];
    const float* fib = (const float*)d_in[10];
    const float* fhw = (const float*)d_in[11];
    const float* fhb = (const float*)d_in[12];
    float* out = (float*)d_out;

    char* ws = (char*)d_ws;
    u16* hb   = (u16*)(ws + OFF_HB);
    u16* cb   = (u16*)(ws + OFF_CB);
    u16* pre  = (u16*)(ws + OFF_PRE);
    u16* Wxb  = (u16*)(ws + OFF_WXB);
    u16* Whb  = (u16*)(ws + OFF_WHB);
    u16* Xb   = (u16*)(ws + OFF_XB);
    u16* pIU  = (u16*)(ws + OFF_PIU);
    float* fc = (float*)(ws + OFF_FC);
    u16* hsb  = (u16*)(ws + OFF_HSB);
    float* bI = (float*)(ws + OFF_BI);
    float* bU = (float*)(ws + OFF_BU);
    float* bF = (float*)(ws + OFF_BF);

    conv_all<<<2912, 256, 0, stream>>>(X, ixw, uxw, fiw, ihw, uhw, fhw,
        ixb, ihb, uxb, uhb, fib, fhb,
        (u32*)Xb, (u32*)Wxb, (u32*)Whb, hb, cb, bI, bU, bF);

    lp_gemm<<<2304, 256, 0, stream>>>(Xb, Wxb, bI, bU, hb, cb, pre);

    const int starts[8] = {5461, 1365, 341, 85, 21, 5, 1, 0};
    const int ends[8]   = {16384, 5461, 1365, 341, 85, 21, 5, 1};
    for (int l = 0; l < 8; ++l) {
        const int s = starts[l], e = ends[l];
        const int L = e - s;
        const int crow0 = 4 * s + 1;
        const int nIUrb = (L + 127) >> 7;
        const int nFrb  = (4 * L + 127) >> 7;
        rec_gemm<<<nIUrb * 4 + nFrb * 2, 256, 0, stream>>>(hb, hsb, Whb, pre, bF, cb,
            pIU, fc, s, crow0, L, (l == 0) ? 1 : 0);
        const int ng = (L + 3) >> 2;
        const int gateBlocks = (ng + 1) >> 1;
        const int hsBlocks = (l == 0) ? 683 : 0;
        gate_kernel<<<gateBlocks + hsBlocks, 256, 0, stream>>>(
            (const u32*)pre, (const u32*)pIU, fc, bI, bU,
            (u32*)hb, (u32*)cb, (u32*)hsb, out, s, L);
    }
}